// Round 2
// baseline (1302.967 us; speedup 1.0000x reference)
//
#include <hip/hip_runtime.h>
#include <stdint.h>

#define H     1024
#define S     2048
#define SEQE  2048
#define NHEAD 16
#define HD    64
#define INNER 4096
#define EPSLN 1e-5f

typedef __attribute__((ext_vector_type(8))) short short8;
typedef __attribute__((ext_vector_type(4))) float floatx4;

__device__ __forceinline__ float b2f(unsigned short u){
  union { unsigned int i; float f; } v; v.i = ((unsigned int)u) << 16; return v.f;
}
__device__ __forceinline__ unsigned short f2b(float f){
  union { float f; unsigned int i; } v; v.f = f;
  unsigned int x = v.i;
  unsigned int r = (x + 0x7FFFu + ((x >> 16) & 1u)) >> 16;
  return (unsigned short)r;
}
__device__ __forceinline__ void unpack8(uint4 v, float* f){
  f[0]=b2f(v.x & 0xFFFFu); f[1]=b2f(v.x>>16);
  f[2]=b2f(v.y & 0xFFFFu); f[3]=b2f(v.y>>16);
  f[4]=b2f(v.z & 0xFFFFu); f[5]=b2f(v.z>>16);
  f[6]=b2f(v.w & 0xFFFFu); f[7]=b2f(v.w>>16);
}
__device__ __forceinline__ float gelu_tanh(float x){
  float x3 = x*x*x;
  float t = tanhf(0.7978845608028654f*(x + 0.044715f*x3));
  return 0.5f*x*(1.0f+t);
}

// ---------------- dtype sniff: flag=1 if d_in[0] is fp32-packed, 0 if bf16 ----------------
__global__ __launch_bounds__(256) void k_sniff(
    const unsigned short* __restrict__ p, int* __restrict__ flag){
  __shared__ int any;
  if (threadIdx.x == 0) any = 0;
  __syncthreads();
  int bad = 0;
  for (int i = threadIdx.x; i < 8192; i += 256){
    float v = b2f(p[i]);
    if (!(fabsf(v) < 1e6f)) bad = 1;   // catches huge / inf / NaN
  }
  if (bad) any = 1;                     // benign race: all write 1
  __syncthreads();
  if (threadIdx.x == 0) flag[0] = any;
}

// ---------------- flag-aware convert -> bf16 (big tensor) ----------------
__global__ __launch_bounds__(256) void k_cvt(
    const void* __restrict__ src, unsigned short* __restrict__ dst, int n,
    const int* __restrict__ flag){
  int i = blockIdx.x * 256 + threadIdx.x;
  if (i < n)
    dst[i] = flag[0] ? f2b(((const float*)src)[i]) : ((const unsigned short*)src)[i];
}

// ---------------- fused small-tensor convert ----------------
struct SmallCvt {
  const void* src[16];
  unsigned short* dst[16];
  int n[16];
};
__global__ __launch_bounds__(256) void k_cvt_small(SmallCvt sc, const int* __restrict__ flag){
  int t = blockIdx.x;
  int fl = flag[0];
  const float* sf = (const float*)sc.src[t];
  const unsigned short* sb = (const unsigned short*)sc.src[t];
  unsigned short* d = sc.dst[t];
  for (int i = threadIdx.x; i < sc.n[t]; i += 256)
    d[i] = fl ? f2b(sf[i]) : sb[i];
}

// ---------------- transpose W[R][C] -> WT[C][R], flag-aware read, bf16 out ----------------
__global__ __launch_bounds__(256) void k_transpose(
    const void* __restrict__ srcv, unsigned short* __restrict__ dst,
    int R, int C, const int* __restrict__ flag){
  __shared__ unsigned short t[32][33];
  const float* sf = (const float*)srcv;
  const unsigned short* sb = (const unsigned short*)srcv;
  int fl = flag[0];
  int bc = blockIdx.x * 32, br = blockIdx.y * 32;
  int tx = threadIdx.x, ty = threadIdx.y;
  #pragma unroll
  for (int i = 0; i < 4; i++){
    size_t idx = (size_t)(br + ty + i*8) * C + bc + tx;
    t[ty + i*8][tx] = fl ? f2b(sf[idx]) : sb[idx];
  }
  __syncthreads();
  #pragma unroll
  for (int i = 0; i < 4; i++)
    dst[(size_t)(bc + ty + i*8) * R + br + tx] = t[tx][ty + i*8];
}

// ---------------- residual init: input (flag dtype) -> fp32 ----------------
__global__ __launch_bounds__(256) void k_resid_init(
    const void* __restrict__ in, float* __restrict__ out, int n,
    const int* __restrict__ flag){
  int i = blockIdx.x * 256 + threadIdx.x;
  if (i < n)
    out[i] = flag[0] ? ((const float*)in)[i] : b2f(((const unsigned short*)in)[i]);
}

// ---------------- LayerNorm over H=1024 (fp32 in, bf16 out), one row/block ----------------
__global__ __launch_bounds__(256) void k_layernorm(
    const float* __restrict__ x,
    const unsigned short* __restrict__ g, const unsigned short* __restrict__ bb,
    unsigned short* __restrict__ y){
  __shared__ float scratch[4];
  int row = blockIdx.x, tid = threadIdx.x;
  float v[4];
  #pragma unroll
  for (int i=0;i<4;i++) v[i] = x[(size_t)row*H + tid + i*256];
  float s = v[0]+v[1]+v[2]+v[3];
  for (int o=32;o;o>>=1) s += __shfl_xor(s,o,64);
  int wid = tid>>6, lane = tid&63;
  if (lane==0) scratch[wid]=s;
  __syncthreads();
  float mu = (scratch[0]+scratch[1]+scratch[2]+scratch[3]) * (1.0f/H);
  __syncthreads();
  float q = 0.f;
  #pragma unroll
  for (int i=0;i<4;i++){ float d=v[i]-mu; q += d*d; }
  for (int o=32;o;o>>=1) q += __shfl_xor(q,o,64);
  if (lane==0) scratch[wid]=q;
  __syncthreads();
  float var = (scratch[0]+scratch[1]+scratch[2]+scratch[3]) * (1.0f/H);
  float rstd = rsqrtf(var + EPSLN);
  #pragma unroll
  for (int i=0;i<4;i++){
    int idx = tid + i*256;
    float o = (v[i]-mu)*rstd*b2f(g[idx]) + b2f(bb[idx]);
    y[(size_t)row*H + idx] = f2b(o);
  }
}

// ---------------- bf16 MFMA GEMM: C[M,N] = A[M,K] * BT[N,K]^T + bias ----------------
// mode 0: out = bf16(v)        mode 1: out = bf16(gelu(v))
// mode 2: resid[m,n] += v (fp32 in-place)
// mode 3: out = (v + resid[m,n]) stored per flag (fp32 or bf16)
__global__ __launch_bounds__(256) void k_gemm_bt(
    const unsigned short* __restrict__ A, const unsigned short* __restrict__ BT,
    const unsigned short* __restrict__ bias,
    unsigned short* __restrict__ outb, float* __restrict__ resid,
    int M, int N, int K, int mode, const int* __restrict__ flag)
{
  __shared__ __align__(16) unsigned short As[128*32];
  __shared__ __align__(16) unsigned short Bs[128*32];
  int tid = threadIdx.x;
  int bm0 = blockIdx.y * 128, bn0 = blockIdx.x * 128;
  int wid = tid >> 6, lane = tid & 63;
  int wm = (wid >> 1) * 64, wn = (wid & 1) * 64;
  int fl = (mode == 3) ? flag[0] : 0;
  floatx4 acc[4][4] = {};
  int r = tid >> 1, hh = (tid & 1) * 16;
  const unsigned short* aptr = A  + (size_t)(bm0 + r) * K + hh;
  const unsigned short* bptr = BT + (size_t)(bn0 + r) * K + hh;
  unsigned short* asw = &As[r*32 + hh];
  unsigned short* bsw = &Bs[r*32 + hh];
  int mrow = lane & 15, kq = (lane >> 4) * 8;
  const unsigned short* afp = &As[(wm + mrow)*32 + kq];
  const unsigned short* bfp = &Bs[(wn + mrow)*32 + kq];
  for (int kt = 0; kt < K; kt += 32){
    uint4 a0 = *(const uint4*)(aptr + kt);
    uint4 a1 = *(const uint4*)(aptr + kt + 8);
    uint4 b0 = *(const uint4*)(bptr + kt);
    uint4 b1 = *(const uint4*)(bptr + kt + 8);
    *(uint4*)asw = a0; *(uint4*)(asw + 8) = a1;
    *(uint4*)bsw = b0; *(uint4*)(bsw + 8) = b1;
    __syncthreads();
    short8 af[4], bfv[4];
    #pragma unroll
    for (int i=0;i<4;i++) af[i]  = *(const short8*)(afp + i*16*32);
    #pragma unroll
    for (int j=0;j<4;j++) bfv[j] = *(const short8*)(bfp + j*16*32);
    #pragma unroll
    for (int i=0;i<4;i++){
      #pragma unroll
      for (int j=0;j<4;j++){
        acc[i][j] = __builtin_amdgcn_mfma_f32_16x16x32_bf16(af[i], bfv[j], acc[i][j], 0,0,0);
      }
    }
    __syncthreads();
  }
  int colb = lane & 15, rowb = (lane >> 4) * 4;
  #pragma unroll
  for (int i=0;i<4;i++){
    #pragma unroll
    for (int j=0;j<4;j++){
      int col = bn0 + wn + j*16 + colb;
      float bv = b2f(bias[col]);
      #pragma unroll
      for (int rr=0;rr<4;rr++){
        int row = bm0 + wm + i*16 + rowb + rr;
        float v = acc[i][j][rr] + bv;
        size_t off = (size_t)row*N + col;
        if      (mode == 0){ outb[off] = f2b(v); }
        else if (mode == 1){ outb[off] = f2b(gelu_tanh(v)); }
        else if (mode == 2){ resid[off] += v; }
        else {
          float o = v + resid[off];
          if (fl) ((float*)outb)[off] = o;
          else    outb[off] = f2b(o);
        }
      }
    }
  }
}

// ---------------- attention: one block per (query row, head) ----------------
// kl = min(S, q + 1 + causal_add): causal_add=0 self-attn, 2 cross (tril diag=2)
// scorer: optional additive per-key bias (canonical bf16), nullptr for self-attn
__global__ __launch_bounds__(256) void k_attn(
    const unsigned short* __restrict__ qb, int qstride,
    const unsigned short* __restrict__ kb, int kstride,
    const unsigned short* __restrict__ vb, int vstride,
    const unsigned short* __restrict__ scorer,
    unsigned short* __restrict__ out, int causal_add)
{
  __shared__ float sc[S];
  __shared__ float red[32*64];
  __shared__ float rtmp[4];
  int qi = blockIdx.x, h = blockIdx.y, tid = threadIdx.x;
  int wid = tid >> 6, lane = tid & 63;
  int kl = qi + 1 + causal_add; if (kl > S) kl = S;
  int klane = tid >> 3;        // 0..31 key lane
  int dg = (tid & 7) * 8;      // 8-dim group within HD=64
  float qreg[8];
  {
    uint4 qv = *(const uint4*)(qb + (size_t)qi*qstride + h*HD + dg);
    unpack8(qv, qreg);
    #pragma unroll
    for (int j=0;j<8;j++) qreg[j] *= 0.125f;   // 1/sqrt(HD)
  }
  // scores
  for (int k = klane; k < kl; k += 32){
    uint4 kv8 = *(const uint4*)(kb + (size_t)k*kstride + h*HD + dg);
    float kf[8]; unpack8(kv8, kf);
    float d = 0.f;
    #pragma unroll
    for (int j=0;j<8;j++) d = fmaf(qreg[j], kf[j], d);
    d += __shfl_xor(d,1,64); d += __shfl_xor(d,2,64); d += __shfl_xor(d,4,64);
    if ((tid & 7) == 0){
      float bias = scorer ? b2f(scorer[k]) : 0.f;
      sc[k] = d + bias;
    }
  }
  __syncthreads();
  // max
  float m = -3.0e38f;
  for (int k = tid; k < kl; k += 256) m = fmaxf(m, sc[k]);
  for (int o=32;o;o>>=1) m = fmaxf(m, __shfl_xor(m,o,64));
  if (lane==0) rtmp[wid] = m;
  __syncthreads();
  m = fmaxf(fmaxf(rtmp[0],rtmp[1]), fmaxf(rtmp[2],rtmp[3]));
  __syncthreads();
  // exp + sum
  float s = 0.f;
  for (int k = tid; k < kl; k += 256){ float p = __expf(sc[k]-m); sc[k] = p; s += p; }
  for (int o=32;o;o>>=1) s += __shfl_xor(s,o,64);
  if (lane==0) rtmp[wid] = s;
  __syncthreads();
  float l = rtmp[0]+rtmp[1]+rtmp[2]+rtmp[3];
  float invl = 1.0f / l;
  // P @ V
  float acc[8] = {0,0,0,0,0,0,0,0};
  for (int k = klane; k < kl; k += 32){
    float p = sc[k];
    uint4 vv = *(const uint4*)(vb + (size_t)k*vstride + h*HD + dg);
    float vf[8]; unpack8(vv, vf);
    #pragma unroll
    for (int j=0;j<8;j++) acc[j] = fmaf(p, vf[j], acc[j]);
  }
  #pragma unroll
  for (int j=0;j<8;j++) red[klane*64 + dg + j] = acc[j];
  __syncthreads();
  if (tid < 64){
    float s2 = 0.f;
    for (int g2 = 0; g2 < 32; g2++) s2 += red[g2*64 + tid];
    out[(size_t)qi*H + h*HD + tid] = f2b(s2 * invl);
  }
}

extern "C" void kernel_launch(void* const* d_in, const int* in_sizes, int n_in,
                              void* d_out, int out_size, void* d_ws, size_t ws_size,
                              hipStream_t stream)
{
  const void* hs          = d_in[0];
  const void* enc         = d_in[1];
  const void* scorer      = d_in[2];
  const void* ln1_g       = d_in[3];
  const void* ln1_b       = d_in[4];
  const void* c_attn_w    = d_in[5];
  const void* c_attn_b    = d_in[6];
  const void* attn_proj_w = d_in[7];
  const void* attn_proj_b = d_in[8];
  const void* lnx_g       = d_in[9];
  const void* lnx_b       = d_in[10];
  const void* q_attn_w    = d_in[11];
  const void* q_attn_b    = d_in[12];
  const void* x_kv_w      = d_in[13];
  const void* x_kv_b      = d_in[14];
  const void* x_proj_w    = d_in[15];
  const void* x_proj_b    = d_in[16];
  const void* ln2_g       = d_in[17];
  const void* ln2_b       = d_in[18];
  const void* fc_w        = d_in[19];
  const void* fc_b        = d_in[20];
  const void* mlp_proj_w  = d_in[21];
  const void* mlp_proj_b  = d_in[22];
  unsigned short* out = (unsigned short*)d_out;

  char* ws = (char*)d_ws; size_t off = 0;
  auto alloc = [&](size_t bytes)->void*{
    void* p = ws + off; off += (bytes + 255) & ~(size_t)255; return p;
  };
  unsigned short* wT_cattn = (unsigned short*)alloc((size_t)3072*1024*2);
  unsigned short* wT_aproj = (unsigned short*)alloc((size_t)1024*1024*2);
  unsigned short* wT_qattn = (unsigned short*)alloc((size_t)1024*1024*2);
  unsigned short* wT_xkv   = (unsigned short*)alloc((size_t)2048*1024*2);
  unsigned short* wT_xproj = (unsigned short*)alloc((size_t)1024*1024*2);
  unsigned short* wT_fc    = (unsigned short*)alloc((size_t)4096*1024*2);
  unsigned short* wT_mlp   = (unsigned short*)alloc((size_t)1024*4096*2);
  unsigned short* enc_c    = (unsigned short*)alloc((size_t)SEQE*H*2);
  unsigned short* canon    = (unsigned short*)alloc((size_t)32768*2);  // small params
  unsigned short* xln      = (unsigned short*)alloc((size_t)S*H*2);
  unsigned short* qkv      = (unsigned short*)alloc((size_t)S*3*H*2);
  unsigned short* attnout  = (unsigned short*)alloc((size_t)S*H*2);
  unsigned short* q2       = (unsigned short*)alloc((size_t)S*H*2);
  unsigned short* kvbuf    = (unsigned short*)alloc((size_t)SEQE*2*H*2);
  unsigned short* fcbuf    = (unsigned short*)alloc((size_t)S*INNER*2);
  float*          hidden   = (float*)alloc((size_t)S*H*4);
  int*            flag     = (int*)alloc(256);

  // canonical small params carved from `canon`
  unsigned short* p = canon;
  auto carve = [&](int n)->unsigned short*{ unsigned short* q = p; p += n; return q; };
  unsigned short* c_ln1g = carve(1024); unsigned short* c_ln1b = carve(1024);
  unsigned short* c_catb = carve(3072); unsigned short* c_aprb = carve(1024);
  unsigned short* c_lnxg = carve(1024); unsigned short* c_lnxb = carve(1024);
  unsigned short* c_qatb = carve(1024); unsigned short* c_xkvb = carve(2048);
  unsigned short* c_xprb = carve(1024); unsigned short* c_ln2g = carve(1024);
  unsigned short* c_ln2b = carve(1024); unsigned short* c_fcb  = carve(4096);
  unsigned short* c_mlpb = carve(1024); unsigned short* c_scor = carve(2048);

  // 1. dtype sniff
  k_sniff<<<1, 256, 0, stream>>>((const unsigned short*)hs, flag);

  // 2. residual init (fp32)
  k_resid_init<<<(S*H)/256, 256, 0, stream>>>(hs, hidden, S*H, flag);

  // 3. weight transposes (flag-aware convert): src[R][C] -> dst[C][R]
  dim3 tb(32,8);
  k_transpose<<<dim3(3072/32,1024/32), tb, 0, stream>>>(c_attn_w,    wT_cattn, 1024, 3072, flag);
  k_transpose<<<dim3(1024/32,1024/32), tb, 0, stream>>>(attn_proj_w, wT_aproj, 1024, 1024, flag);
  k_transpose<<<dim3(1024/32,1024/32), tb, 0, stream>>>(q_attn_w,    wT_qattn, 1024, 1024, flag);
  k_transpose<<<dim3(2048/32,1024/32), tb, 0, stream>>>(x_kv_w,      wT_xkv,   1024, 2048, flag);
  k_transpose<<<dim3(1024/32,1024/32), tb, 0, stream>>>(x_proj_w,    wT_xproj, 1024, 1024, flag);
  k_transpose<<<dim3(4096/32,1024/32), tb, 0, stream>>>(fc_w,        wT_fc,    1024, 4096, flag);
  k_transpose<<<dim3(1024/32,4096/32), tb, 0, stream>>>(mlp_proj_w,  wT_mlp,   4096, 1024, flag);

  // 4. canonicalize encoder states + small params
  k_cvt<<<(SEQE*H)/256, 256, 0, stream>>>(enc, enc_c, SEQE*H, flag);
  SmallCvt sc{};
  const void* ssrc[14] = {ln1_g, ln1_b, c_attn_b, attn_proj_b, lnx_g, lnx_b,
                          q_attn_b, x_kv_b, x_proj_b, ln2_g, ln2_b, fc_b,
                          mlp_proj_b, scorer};
  unsigned short* sdst[14] = {c_ln1g, c_ln1b, c_catb, c_aprb, c_lnxg, c_lnxb,
                              c_qatb, c_xkvb, c_xprb, c_ln2g, c_ln2b, c_fcb,
                              c_mlpb, c_scor};
  int sn[14] = {1024,1024,3072,1024,1024,1024,1024,2048,1024,1024,1024,4096,1024,2048};
  for (int i=0;i<14;i++){ sc.src[i]=ssrc[i]; sc.dst[i]=sdst[i]; sc.n[i]=sn[i]; }
  k_cvt_small<<<14, 256, 0, stream>>>(sc, flag);

  // --- self attention ---
  k_layernorm<<<S, 256, 0, stream>>>(hidden, c_ln1g, c_ln1b, xln);
  k_gemm_bt<<<dim3(3072/128, S/128), 256, 0, stream>>>(xln, wT_cattn, c_catb,
                                                       qkv, nullptr, S, 3072, 1024, 0, flag);
  k_attn<<<dim3(S, NHEAD), 256, 0, stream>>>(qkv, 3*H, qkv + H, 3*H, qkv + 2*H, 3*H,
                                             nullptr, attnout, 0);
  k_gemm_bt<<<dim3(1024/128, S/128), 256, 0, stream>>>(attnout, wT_aproj, c_aprb,
                                                       nullptr, hidden, S, 1024, 1024, 2, flag);

  // --- cross attention ---
  k_layernorm<<<S, 256, 0, stream>>>(hidden, c_lnxg, c_lnxb, xln);
  k_gemm_bt<<<dim3(1024/128, S/128), 256, 0, stream>>>(xln, wT_qattn, c_qatb,
                                                       q2, nullptr, S, 1024, 1024, 0, flag);
  k_gemm_bt<<<dim3(2048/128, SEQE/128), 256, 0, stream>>>(enc_c, wT_xkv, c_xkvb,
                                                          kvbuf, nullptr, SEQE, 2048, 1024, 0, flag);
  k_attn<<<dim3(S, NHEAD), 256, 0, stream>>>(q2, H, kvbuf, 2*H, kvbuf + H, 2*H,
                                             c_scor, attnout, 2);
  k_gemm_bt<<<dim3(1024/128, S/128), 256, 0, stream>>>(attnout, wT_xproj, c_xprb,
                                                       nullptr, hidden, S, 1024, 1024, 2, flag);

  // --- MLP ---
  k_layernorm<<<S, 256, 0, stream>>>(hidden, c_ln2g, c_ln2b, xln);
  k_gemm_bt<<<dim3(INNER/128, S/128), 256, 0, stream>>>(xln, wT_fc, c_fcb,
                                                        fcbuf, nullptr, S, INNER, 1024, 1, flag);
  k_gemm_bt<<<dim3(1024/128, S/128), 256, 0, stream>>>(fcbuf, wT_mlp, c_mlpb,
                                                       out, hidden, S, 1024, INNER, 3, flag);
}

// Round 3
// 716.627 us; speedup vs baseline: 1.8182x; 1.8182x over previous
//
#include <hip/hip_runtime.h>
#include <stdint.h>

#define H     1024
#define S     2048
#define SEQE  2048
#define NHEAD 16
#define HD    64
#define INNER 4096
#define EPSLN 1e-5f

typedef __attribute__((ext_vector_type(8))) short short8;
typedef __attribute__((ext_vector_type(4))) float floatx4;

__device__ __forceinline__ float b2f(unsigned short u){
  union { unsigned int i; float f; } v; v.i = ((unsigned int)u) << 16; return v.f;
}
__device__ __forceinline__ unsigned short f2b(float f){
  union { float f; unsigned int i; } v; v.f = f;
  unsigned int x = v.i;
  unsigned int r = (x + 0x7FFFu + ((x >> 16) & 1u)) >> 16;
  return (unsigned short)r;
}
__device__ __forceinline__ float gelu_tanh(float x){
  float x3 = x*x*x;
  float t = tanhf(0.7978845608028654f*(x + 0.044715f*x3));
  return 0.5f*x*(1.0f+t);
}

// ---------------- dtype sniff: flag=1 if d_in[0] is fp32-packed, 0 if bf16 ----------------
__global__ __launch_bounds__(256) void k_sniff(
    const unsigned short* __restrict__ p, int* __restrict__ flag){
  __shared__ int any;
  if (threadIdx.x == 0) any = 0;
  __syncthreads();
  int bad = 0;
  for (int i = threadIdx.x; i < 8192; i += 256){
    float v = b2f(p[i]);
    if (!(fabsf(v) < 1e6f)) bad = 1;
  }
  if (bad) any = 1;
  __syncthreads();
  if (threadIdx.x == 0) flag[0] = any;
}

// ---------------- flag-aware convert -> bf16 (big tensor) ----------------
__global__ __launch_bounds__(256) void k_cvt(
    const void* __restrict__ src, unsigned short* __restrict__ dst, int n,
    const int* __restrict__ flag){
  int i = blockIdx.x * 256 + threadIdx.x;
  if (i < n)
    dst[i] = flag[0] ? f2b(((const float*)src)[i]) : ((const unsigned short*)src)[i];
}

// ---------------- fused small-tensor convert ----------------
struct SmallCvt {
  const void* src[16];
  unsigned short* dst[16];
  int n[16];
};
__global__ __launch_bounds__(256) void k_cvt_small(SmallCvt sc, const int* __restrict__ flag){
  int t = blockIdx.x;
  int fl = flag[0];
  const float* sf = (const float*)sc.src[t];
  const unsigned short* sb = (const unsigned short*)sc.src[t];
  unsigned short* d = sc.dst[t];
  for (int i = threadIdx.x; i < sc.n[t]; i += 256)
    d[i] = fl ? f2b(sf[i]) : sb[i];
}

// ---------------- transpose W[R][C] -> WT[C][R], flag-aware read, bf16 out ----------------
__global__ __launch_bounds__(256) void k_transpose(
    const void* __restrict__ srcv, unsigned short* __restrict__ dst,
    int R, int C, const int* __restrict__ flag){
  __shared__ unsigned short t[32][33];
  const float* sf = (const float*)srcv;
  const unsigned short* sb = (const unsigned short*)srcv;
  int fl = flag[0];
  int bc = blockIdx.x * 32, br = blockIdx.y * 32;
  int tx = threadIdx.x, ty = threadIdx.y;
  #pragma unroll
  for (int i = 0; i < 4; i++){
    size_t idx = (size_t)(br + ty + i*8) * C + bc + tx;
    t[ty + i*8][tx] = fl ? f2b(sf[idx]) : sb[idx];
  }
  __syncthreads();
  #pragma unroll
  for (int i = 0; i < 4; i++)
    dst[(size_t)(bc + ty + i*8) * R + br + tx] = t[tx][ty + i*8];
}

// ---------------- residual init: input (flag dtype) -> fp32 ----------------
__global__ __launch_bounds__(256) void k_resid_init(
    const void* __restrict__ in, float* __restrict__ out, int n,
    const int* __restrict__ flag){
  int i = blockIdx.x * 256 + threadIdx.x;
  if (i < n)
    out[i] = flag[0] ? ((const float*)in)[i] : b2f(((const unsigned short*)in)[i]);
}

// ---------------- LayerNorm over H=1024 (fp32 in, bf16 out), one row/block ----------------
__global__ __launch_bounds__(256) void k_layernorm(
    const float* __restrict__ x,
    const unsigned short* __restrict__ g, const unsigned short* __restrict__ bb,
    unsigned short* __restrict__ y){
  __shared__ float scratch[4];
  int row = blockIdx.x, tid = threadIdx.x;
  float v[4];
  #pragma unroll
  for (int i=0;i<4;i++) v[i] = x[(size_t)row*H + tid + i*256];
  float s = v[0]+v[1]+v[2]+v[3];
  for (int o=32;o;o>>=1) s += __shfl_xor(s,o,64);
  int wid = tid>>6, lane = tid&63;
  if (lane==0) scratch[wid]=s;
  __syncthreads();
  float mu = (scratch[0]+scratch[1]+scratch[2]+scratch[3]) * (1.0f/H);
  __syncthreads();
  float q = 0.f;
  #pragma unroll
  for (int i=0;i<4;i++){ float d=v[i]-mu; q += d*d; }
  for (int o=32;o;o>>=1) q += __shfl_xor(q,o,64);
  if (lane==0) scratch[wid]=q;
  __syncthreads();
  float var = (scratch[0]+scratch[1]+scratch[2]+scratch[3]) * (1.0f/H);
  float rstd = rsqrtf(var + EPSLN);
  #pragma unroll
  for (int i=0;i<4;i++){
    int idx = tid + i*256;
    float o = (v[i]-mu)*rstd*b2f(g[idx]) + b2f(bb[idx]);
    y[(size_t)row*H + idx] = f2b(o);
  }
}

// ---------------- bf16 MFMA GEMM: C[M,N] = A[M,K] * BT[N,K]^T + bias ----------------
// mode 0: out = bf16(v)        mode 1: out = bf16(gelu(v))
// mode 2: resid[m,n] += v (fp32 in-place)
// mode 3: out = (v + resid[m,n]) stored per flag (fp32 or bf16)
// mode 4: col < vcol0 -> natural bf16; col >= vcol0 -> transposed write
//         vtout[(col-vcol0)*M + row]  (per-head V^T for flash attention)
__global__ __launch_bounds__(256) void k_gemm_bt(
    const unsigned short* __restrict__ A, const unsigned short* __restrict__ BT,
    const unsigned short* __restrict__ bias,
    unsigned short* __restrict__ outb, float* __restrict__ resid,
    int M, int N, int K, int mode, const int* __restrict__ flag,
    int vcol0, unsigned short* __restrict__ vtout)
{
  __shared__ __align__(16) unsigned short As[128*32];
  __shared__ __align__(16) unsigned short Bs[128*32];
  int tid = threadIdx.x;
  int bm0 = blockIdx.y * 128, bn0 = blockIdx.x * 128;
  int wid = tid >> 6, lane = tid & 63;
  int wm = (wid >> 1) * 64, wn = (wid & 1) * 64;
  int fl = (mode == 3) ? flag[0] : 0;
  floatx4 acc[4][4] = {};
  int r = tid >> 1, hh = (tid & 1) * 16;
  const unsigned short* aptr = A  + (size_t)(bm0 + r) * K + hh;
  const unsigned short* bptr = BT + (size_t)(bn0 + r) * K + hh;
  unsigned short* asw = &As[r*32 + hh];
  unsigned short* bsw = &Bs[r*32 + hh];
  int mrow = lane & 15, kq = (lane >> 4) * 8;
  const unsigned short* afp = &As[(wm + mrow)*32 + kq];
  const unsigned short* bfp = &Bs[(wn + mrow)*32 + kq];
  for (int kt = 0; kt < K; kt += 32){
    uint4 a0 = *(const uint4*)(aptr + kt);
    uint4 a1 = *(const uint4*)(aptr + kt + 8);
    uint4 b0 = *(const uint4*)(bptr + kt);
    uint4 b1 = *(const uint4*)(bptr + kt + 8);
    *(uint4*)asw = a0; *(uint4*)(asw + 8) = a1;
    *(uint4*)bsw = b0; *(uint4*)(bsw + 8) = b1;
    __syncthreads();
    short8 af[4], bfv[4];
    #pragma unroll
    for (int i=0;i<4;i++) af[i]  = *(const short8*)(afp + i*16*32);
    #pragma unroll
    for (int j=0;j<4;j++) bfv[j] = *(const short8*)(bfp + j*16*32);
    #pragma unroll
    for (int i=0;i<4;i++){
      #pragma unroll
      for (int j=0;j<4;j++){
        acc[i][j] = __builtin_amdgcn_mfma_f32_16x16x32_bf16(af[i], bfv[j], acc[i][j], 0,0,0);
      }
    }
    __syncthreads();
  }
  int colb = lane & 15, rowb = (lane >> 4) * 4;
  #pragma unroll
  for (int i=0;i<4;i++){
    #pragma unroll
    for (int j=0;j<4;j++){
      int col = bn0 + wn + j*16 + colb;
      float bv = b2f(bias[col]);
      int row0 = bm0 + wm + i*16 + rowb;
      if (mode == 4 && col >= vcol0){
        ushort4 uv;
        uv.x = f2b(acc[i][j][0] + bv);
        uv.y = f2b(acc[i][j][1] + bv);
        uv.z = f2b(acc[i][j][2] + bv);
        uv.w = f2b(acc[i][j][3] + bv);
        *(ushort4*)(vtout + (size_t)(col - vcol0)*M + row0) = uv;
      } else {
        #pragma unroll
        for (int rr=0;rr<4;rr++){
          int row = row0 + rr;
          float v = acc[i][j][rr] + bv;
          size_t off = (size_t)row*N + col;
          if      (mode == 0 || mode == 4){ outb[off] = f2b(v); }
          else if (mode == 1){ outb[off] = f2b(gelu_tanh(v)); }
          else if (mode == 2){ resid[off] += v; }
          else {
            float o = v + resid[off];
            if (fl) ((float*)outb)[off] = o;
            else    outb[off] = f2b(o);
          }
        }
      }
    }
  }
}

// ---------------- flash attention (MFMA) ----------------
// Block: 4 waves, 64 Q-rows (16 per wave), one head. K processed in 64-chunks.
// CA: causal extra diagonal (0 self, 2 cross). SCOR: add scorer[k] bias.
// vt: per-head transposed V, vt[(h*64+d)*S + n].
template<int CA, int SCOR>
__global__ __launch_bounds__(256) void k_flash(
    const unsigned short* __restrict__ qb, int qstride,
    const unsigned short* __restrict__ kb, int kstride,
    const unsigned short* __restrict__ vt,
    const unsigned short* __restrict__ scorer,
    unsigned short* __restrict__ out)
{
  __shared__ __align__(16) unsigned short Ks[64*72];   // K tile [n][d], stride 72
  __shared__ __align__(16) unsigned short VTs[64*72];  // V^T tile [d][n], stride 72
  __shared__ __align__(16) unsigned short Ps[4][16*72];// per-wave P [m][n], stride 72
  __shared__ float scs[64];
  int tid = threadIdx.x;
  int q0 = blockIdx.x * 64, h = blockIdx.y;
  int w = tid >> 6, lane = tid & 63;
  int cn = lane & 15, quad = lane >> 4, kq = quad * 8;
  unsigned short* Pw = Ps[w];
  // Q fragments (A operand): m = cn within wave tile, k = kq+j (+32)
  const unsigned short* qrow = qb + (size_t)(q0 + w*16 + cn) * qstride + h*HD;
  short8 qf0 = *(const short8*)(qrow + kq);
  short8 qf1 = *(const short8*)(qrow + kq + 32);
  floatx4 oacc[4] = {};
  float m_i[4], l_i[4];
  #pragma unroll
  for (int r=0;r<4;r++){ m_i[r] = -3.0e38f; l_i[r] = 0.f; }
  int qmr = q0 + w*16 + quad*4;   // + r gives this lane's Q rows (C layout)
  int sr = tid >> 2, sc2 = (tid & 3) * 16;
  int klmax = q0 + 64 + CA; if (klmax > S) klmax = S;
  for (int kc = 0; kc < klmax; kc += 64){
    __syncthreads();
    {
      const unsigned short* kp = kb + (size_t)(kc + sr) * kstride + h*HD + sc2;
      uint4 a0 = *(const uint4*)kp;
      uint4 a1 = *(const uint4*)(kp + 8);
      const unsigned short* vp = vt + (size_t)(h*HD + sr) * S + kc + sc2;
      uint4 b0 = *(const uint4*)vp;
      uint4 b1 = *(const uint4*)(vp + 8);
      *(uint4*)&Ks[sr*72 + sc2]      = a0;
      *(uint4*)&Ks[sr*72 + sc2 + 8]  = a1;
      *(uint4*)&VTs[sr*72 + sc2]     = b0;
      *(uint4*)&VTs[sr*72 + sc2 + 8] = b1;
      if (SCOR && tid < 64) scs[tid] = b2f(scorer[kc + tid]);
    }
    __syncthreads();
    // S = Q K^T  (rows = Q m, cols = K n)
    floatx4 sv[4] = {};
    #pragma unroll
    for (int t=0;t<4;t++){
      short8 b0 = *(const short8*)&Ks[(t*16 + cn)*72 + kq];
      short8 b1 = *(const short8*)&Ks[(t*16 + cn)*72 + kq + 32];
      sv[t] = __builtin_amdgcn_mfma_f32_16x16x32_bf16(qf0, b0, sv[t], 0,0,0);
      sv[t] = __builtin_amdgcn_mfma_f32_16x16x32_bf16(qf1, b1, sv[t], 0,0,0);
    }
    // online softmax per Q-row r
    #pragma unroll
    for (int r=0;r<4;r++){
      int qlim = qmr + r + CA;
      float mx = -3.0e38f;
      float pv[4];
      #pragma unroll
      for (int t=0;t<4;t++){
        int kn = kc + t*16 + cn;
        float s = sv[t][r] * 0.125f;
        if (SCOR) s += scs[t*16 + cn];
        s = (kn <= qlim) ? s : -3.0e38f;
        pv[t] = s;
        mx = fmaxf(mx, s);
      }
      mx = fmaxf(mx, __shfl_xor(mx,1,64));
      mx = fmaxf(mx, __shfl_xor(mx,2,64));
      mx = fmaxf(mx, __shfl_xor(mx,4,64));
      mx = fmaxf(mx, __shfl_xor(mx,8,64));
      float mnew = fmaxf(m_i[r], mx);
      float al = __expf(m_i[r] - mnew);
      m_i[r] = mnew;
      float sum = 0.f;
      #pragma unroll
      for (int t=0;t<4;t++){
        float e = __expf(pv[t] - mnew);
        sum += e;
        Pw[(quad*4 + r)*72 + t*16 + cn] = f2b(e);
      }
      sum += __shfl_xor(sum,1,64);
      sum += __shfl_xor(sum,2,64);
      sum += __shfl_xor(sum,4,64);
      sum += __shfl_xor(sum,8,64);
      l_i[r] = l_i[r]*al + sum;
      #pragma unroll
      for (int t2=0;t2<4;t2++) oacc[t2][r] *= al;
    }
    // O += P V  (A = P[m][n], B = V^T[d][n])
    short8 pf0 = *(const short8*)&Pw[cn*72 + kq];
    short8 pf1 = *(const short8*)&Pw[cn*72 + kq + 32];
    #pragma unroll
    for (int t2=0;t2<4;t2++){
      short8 v0 = *(const short8*)&VTs[(t2*16 + cn)*72 + kq];
      short8 v1 = *(const short8*)&VTs[(t2*16 + cn)*72 + kq + 32];
      oacc[t2] = __builtin_amdgcn_mfma_f32_16x16x32_bf16(pf0, v0, oacc[t2], 0,0,0);
      oacc[t2] = __builtin_amdgcn_mfma_f32_16x16x32_bf16(pf1, v1, oacc[t2], 0,0,0);
    }
  }
  #pragma unroll
  for (int r=0;r<4;r++){
    float inv = 1.0f / l_i[r];
    size_t rowoff = (size_t)(qmr + r) * H + h*HD;
    #pragma unroll
    for (int t2=0;t2<4;t2++)
      out[rowoff + t2*16 + cn] = f2b(oacc[t2][r] * inv);
  }
}

extern "C" void kernel_launch(void* const* d_in, const int* in_sizes, int n_in,
                              void* d_out, int out_size, void* d_ws, size_t ws_size,
                              hipStream_t stream)
{
  const void* hs          = d_in[0];
  const void* enc         = d_in[1];
  const void* scorer      = d_in[2];
  const void* ln1_g       = d_in[3];
  const void* ln1_b       = d_in[4];
  const void* c_attn_w    = d_in[5];
  const void* c_attn_b    = d_in[6];
  const void* attn_proj_w = d_in[7];
  const void* attn_proj_b = d_in[8];
  const void* lnx_g       = d_in[9];
  const void* lnx_b       = d_in[10];
  const void* q_attn_w    = d_in[11];
  const void* q_attn_b    = d_in[12];
  const void* x_kv_w      = d_in[13];
  const void* x_kv_b      = d_in[14];
  const void* x_proj_w    = d_in[15];
  const void* x_proj_b    = d_in[16];
  const void* ln2_g       = d_in[17];
  const void* ln2_b       = d_in[18];
  const void* fc_w        = d_in[19];
  const void* fc_b        = d_in[20];
  const void* mlp_proj_w  = d_in[21];
  const void* mlp_proj_b  = d_in[22];
  unsigned short* out = (unsigned short*)d_out;

  char* ws = (char*)d_ws; size_t off = 0;
  auto alloc = [&](size_t bytes)->void*{
    void* p = ws + off; off += (bytes + 255) & ~(size_t)255; return p;
  };
  unsigned short* wT_cattn = (unsigned short*)alloc((size_t)3072*1024*2);
  unsigned short* wT_aproj = (unsigned short*)alloc((size_t)1024*1024*2);
  unsigned short* wT_qattn = (unsigned short*)alloc((size_t)1024*1024*2);
  unsigned short* wT_xkv   = (unsigned short*)alloc((size_t)2048*1024*2);
  unsigned short* wT_xproj = (unsigned short*)alloc((size_t)1024*1024*2);
  unsigned short* wT_fc    = (unsigned short*)alloc((size_t)4096*1024*2);
  unsigned short* wT_mlp   = (unsigned short*)alloc((size_t)1024*4096*2);
  unsigned short* enc_c    = (unsigned short*)alloc((size_t)SEQE*H*2);
  unsigned short* canon    = (unsigned short*)alloc((size_t)32768*2);
  unsigned short* xln      = (unsigned short*)alloc((size_t)S*H*2);
  unsigned short* qkv      = (unsigned short*)alloc((size_t)S*3*H*2);
  unsigned short* attnout  = (unsigned short*)alloc((size_t)S*H*2);
  unsigned short* q2       = (unsigned short*)alloc((size_t)S*H*2);
  unsigned short* kvbuf    = (unsigned short*)alloc((size_t)SEQE*2*H*2);
  unsigned short* vt_self  = (unsigned short*)alloc((size_t)H*S*2);
  unsigned short* vt_cross = (unsigned short*)alloc((size_t)H*SEQE*2);
  unsigned short* fcbuf    = (unsigned short*)alloc((size_t)S*INNER*2);
  float*          hidden   = (float*)alloc((size_t)S*H*4);
  int*            flag     = (int*)alloc(256);

  unsigned short* p = canon;
  auto carve = [&](int n)->unsigned short*{ unsigned short* q = p; p += n; return q; };
  unsigned short* c_ln1g = carve(1024); unsigned short* c_ln1b = carve(1024);
  unsigned short* c_catb = carve(3072); unsigned short* c_aprb = carve(1024);
  unsigned short* c_lnxg = carve(1024); unsigned short* c_lnxb = carve(1024);
  unsigned short* c_qatb = carve(1024); unsigned short* c_xkvb = carve(2048);
  unsigned short* c_xprb = carve(1024); unsigned short* c_ln2g = carve(1024);
  unsigned short* c_ln2b = carve(1024); unsigned short* c_fcb  = carve(4096);
  unsigned short* c_mlpb = carve(1024); unsigned short* c_scor = carve(2048);

  // 1. dtype sniff
  k_sniff<<<1, 256, 0, stream>>>((const unsigned short*)hs, flag);

  // 2. residual init (fp32)
  k_resid_init<<<(S*H)/256, 256, 0, stream>>>(hs, hidden, S*H, flag);

  // 3. weight transposes
  dim3 tb(32,8);
  k_transpose<<<dim3(3072/32,1024/32), tb, 0, stream>>>(c_attn_w,    wT_cattn, 1024, 3072, flag);
  k_transpose<<<dim3(1024/32,1024/32), tb, 0, stream>>>(attn_proj_w, wT_aproj, 1024, 1024, flag);
  k_transpose<<<dim3(1024/32,1024/32), tb, 0, stream>>>(q_attn_w,    wT_qattn, 1024, 1024, flag);
  k_transpose<<<dim3(2048/32,1024/32), tb, 0, stream>>>(x_kv_w,      wT_xkv,   1024, 2048, flag);
  k_transpose<<<dim3(1024/32,1024/32), tb, 0, stream>>>(x_proj_w,    wT_xproj, 1024, 1024, flag);
  k_transpose<<<dim3(4096/32,1024/32), tb, 0, stream>>>(fc_w,        wT_fc,    1024, 4096, flag);
  k_transpose<<<dim3(1024/32,4096/32), tb, 0, stream>>>(mlp_proj_w,  wT_mlp,   4096, 1024, flag);

  // 4. canonicalize encoder states + small params
  k_cvt<<<(SEQE*H)/256, 256, 0, stream>>>(enc, enc_c, SEQE*H, flag);
  SmallCvt sc{};
  const void* ssrc[14] = {ln1_g, ln1_b, c_attn_b, attn_proj_b, lnx_g, lnx_b,
                          q_attn_b, x_kv_b, x_proj_b, ln2_g, ln2_b, fc_b,
                          mlp_proj_b, scorer};
  unsigned short* sdst[14] = {c_ln1g, c_ln1b, c_catb, c_aprb, c_lnxg, c_lnxb,
                              c_qatb, c_xkvb, c_xprb, c_ln2g, c_ln2b, c_fcb,
                              c_mlpb, c_scor};
  int sn[14] = {1024,1024,3072,1024,1024,1024,1024,2048,1024,1024,1024,4096,1024,2048};
  for (int i=0;i<14;i++){ sc.src[i]=ssrc[i]; sc.dst[i]=sdst[i]; sc.n[i]=sn[i]; }
  k_cvt_small<<<14, 256, 0, stream>>>(sc, flag);

  // --- self attention ---
  k_layernorm<<<S, 256, 0, stream>>>(hidden, c_ln1g, c_ln1b, xln);
  k_gemm_bt<<<dim3(3072/128, S/128), 256, 0, stream>>>(xln, wT_cattn, c_catb,
      qkv, nullptr, S, 3072, 1024, 4, flag, 2048, vt_self);
  k_flash<0,0><<<dim3(S/64, NHEAD), 256, 0, stream>>>(
      qkv, 3*H, qkv + 1024, 3*H, vt_self, nullptr, attnout);
  k_gemm_bt<<<dim3(1024/128, S/128), 256, 0, stream>>>(attnout, wT_aproj, c_aprb,
      nullptr, hidden, S, 1024, 1024, 2, flag, 0, nullptr);

  // --- cross attention ---
  k_layernorm<<<S, 256, 0, stream>>>(hidden, c_lnxg, c_lnxb, xln);
  k_gemm_bt<<<dim3(1024/128, S/128), 256, 0, stream>>>(xln, wT_qattn, c_qatb,
      q2, nullptr, S, 1024, 1024, 0, flag, 0, nullptr);
  k_gemm_bt<<<dim3(2048/128, SEQE/128), 256, 0, stream>>>(enc_c, wT_xkv, c_xkvb,
      kvbuf, nullptr, SEQE, 2048, 1024, 4, flag, 1024, vt_cross);
  k_flash<2,1><<<dim3(S/64, NHEAD), 256, 0, stream>>>(
      q2, H, kvbuf, 2*H, vt_cross, c_scor, attnout);
  k_gemm_bt<<<dim3(1024/128, S/128), 256, 0, stream>>>(attnout, wT_xproj, c_xprb,
      nullptr, hidden, S, 1024, 1024, 2, flag, 0, nullptr);

  // --- MLP ---
  k_layernorm<<<S, 256, 0, stream>>>(hidden, c_ln2g, c_ln2b, xln);
  k_gemm_bt<<<dim3(INNER/128, S/128), 256, 0, stream>>>(xln, wT_fc, c_fcb,
      fcbuf, nullptr, S, INNER, 1024, 1, flag, 0, nullptr);
  k_gemm_bt<<<dim3(1024/128, S/128), 256, 0, stream>>>(fcbuf, wT_mlp, c_mlpb,
      out, hidden, S, 1024, INNER, 3, flag, 0, nullptr);
}

// Round 4
// 564.719 us; speedup vs baseline: 2.3073x; 1.2690x over previous
//
#include <hip/hip_runtime.h>
#include <stdint.h>

#define H     1024
#define S     2048
#define SEQE  2048
#define NHEAD 16
#define HD    64
#define INNER 4096
#define EPSLN 1e-5f

typedef __attribute__((ext_vector_type(8))) short short8;
typedef __attribute__((ext_vector_type(4))) float floatx4;

__device__ __forceinline__ float b2f(unsigned short u){
  union { unsigned int i; float f; } v; v.i = ((unsigned int)u) << 16; return v.f;
}
__device__ __forceinline__ unsigned short f2b(float f){
  union { float f; unsigned int i; } v; v.f = f;
  unsigned int x = v.i;
  unsigned int r = (x + 0x7FFFu + ((x >> 16) & 1u)) >> 16;
  return (unsigned short)r;
}
__device__ __forceinline__ float gelu_tanh(float x){
  float x3 = x*x*x;
  float t = tanhf(0.7978845608028654f*(x + 0.044715f*x3));
  return 0.5f*x*(1.0f+t);
}

// async global->LDS, 16B per lane; LDS dest = wave-uniform base + lane*16
__device__ __forceinline__ void gld16(const unsigned short* g, unsigned short* l){
  __builtin_amdgcn_global_load_lds(
      (const __attribute__((address_space(1))) unsigned int*)g,
      (__attribute__((address_space(3))) unsigned int*)l,
      16, 0, 0);
}

// ---------------- dtype sniff: flag=1 if d_in[0] is fp32-packed, 0 if bf16 ----------------
__global__ __launch_bounds__(256) void k_sniff(
    const unsigned short* __restrict__ p, int* __restrict__ flag){
  __shared__ int any;
  if (threadIdx.x == 0) any = 0;
  __syncthreads();
  int bad = 0;
  for (int i = threadIdx.x; i < 8192; i += 256){
    float v = b2f(p[i]);
    if (!(fabsf(v) < 1e6f)) bad = 1;
  }
  if (bad) any = 1;
  __syncthreads();
  if (threadIdx.x == 0) flag[0] = any;
}

// ---------------- flag-aware convert -> bf16 (big tensor) ----------------
__global__ __launch_bounds__(256) void k_cvt(
    const void* __restrict__ src, unsigned short* __restrict__ dst, int n,
    const int* __restrict__ flag){
  int i = blockIdx.x * 256 + threadIdx.x;
  if (i < n)
    dst[i] = flag[0] ? f2b(((const float*)src)[i]) : ((const unsigned short*)src)[i];
}

// ---------------- fused small-tensor convert ----------------
struct SmallCvt {
  const void* src[16];
  unsigned short* dst[16];
  int n[16];
};
__global__ __launch_bounds__(256) void k_cvt_small(SmallCvt sc, const int* __restrict__ flag){
  int t = blockIdx.x;
  int fl = flag[0];
  const float* sf = (const float*)sc.src[t];
  const unsigned short* sb = (const unsigned short*)sc.src[t];
  unsigned short* d = sc.dst[t];
  for (int i = threadIdx.x; i < sc.n[t]; i += 256)
    d[i] = fl ? f2b(sf[i]) : sb[i];
}

// ---------------- transpose W[R][C] -> WT[C][R], flag-aware read, bf16 out ----------------
__global__ __launch_bounds__(256) void k_transpose(
    const void* __restrict__ srcv, unsigned short* __restrict__ dst,
    int R, int C, const int* __restrict__ flag){
  __shared__ unsigned short t[32][33];
  const float* sf = (const float*)srcv;
  const unsigned short* sb = (const unsigned short*)srcv;
  int fl = flag[0];
  int bc = blockIdx.x * 32, br = blockIdx.y * 32;
  int tx = threadIdx.x, ty = threadIdx.y;
  #pragma unroll
  for (int i = 0; i < 4; i++){
    size_t idx = (size_t)(br + ty + i*8) * C + bc + tx;
    t[ty + i*8][tx] = fl ? f2b(sf[idx]) : sb[idx];
  }
  __syncthreads();
  #pragma unroll
  for (int i = 0; i < 4; i++)
    dst[(size_t)(bc + ty + i*8) * R + br + tx] = t[tx][ty + i*8];
}

// ---------------- residual init: input (flag dtype) -> fp32 ----------------
__global__ __launch_bounds__(256) void k_resid_init(
    const void* __restrict__ in, float* __restrict__ out, int n,
    const int* __restrict__ flag){
  int i = blockIdx.x * 256 + threadIdx.x;
  if (i < n)
    out[i] = flag[0] ? ((const float*)in)[i] : b2f(((const unsigned short*)in)[i]);
}

// ---------------- LayerNorm over H=1024 (fp32 in, bf16 out), one row/block ----------------
__global__ __launch_bounds__(256) void k_layernorm(
    const float* __restrict__ x,
    const unsigned short* __restrict__ g, const unsigned short* __restrict__ bb,
    unsigned short* __restrict__ y){
  __shared__ float scratch[4];
  int row = blockIdx.x, tid = threadIdx.x;
  float v[4];
  #pragma unroll
  for (int i=0;i<4;i++) v[i] = x[(size_t)row*H + tid + i*256];
  float s = v[0]+v[1]+v[2]+v[3];
  for (int o=32;o;o>>=1) s += __shfl_xor(s,o,64);
  int wid = tid>>6, lane = tid&63;
  if (lane==0) scratch[wid]=s;
  __syncthreads();
  float mu = (scratch[0]+scratch[1]+scratch[2]+scratch[3]) * (1.0f/H);
  __syncthreads();
  float q = 0.f;
  #pragma unroll
  for (int i=0;i<4;i++){ float d=v[i]-mu; q += d*d; }
  for (int o=32;o;o>>=1) q += __shfl_xor(q,o,64);
  if (lane==0) scratch[wid]=q;
  __syncthreads();
  float var = (scratch[0]+scratch[1]+scratch[2]+scratch[3]) * (1.0f/H);
  float rstd = rsqrtf(var + EPSLN);
  #pragma unroll
  for (int i=0;i<4;i++){
    int idx = tid + i*256;
    float o = (v[i]-mu)*rstd*b2f(g[idx]) + b2f(bb[idx]);
    y[(size_t)row*H + idx] = f2b(o);
  }
}

// ---------------- bf16 MFMA GEMM, 64x128 tile, BK=64, async LDS staging ----------------
// C[M,N] = A[M,K] * BT[N,K]^T + bias
// mode 0: out = bf16(v)        mode 1: out = bf16(gelu(v))
// mode 2: resid[m,n] += v (fp32 in-place)
// mode 3: out = (v + resid[m,n]) stored per flag (fp32 or bf16)
// mode 4: col < vcol0 -> natural bf16; col >= vcol0 -> vtout[(col-vcol0)*M + row]
// LDS layout: [row][8 chunks of 8 elems], chunk stored at slot (chunk ^ (row&7))
__global__ __launch_bounds__(256) void k_gemm64(
    const unsigned short* __restrict__ A, const unsigned short* __restrict__ BT,
    const unsigned short* __restrict__ bias,
    unsigned short* __restrict__ outb, float* __restrict__ resid,
    int M, int N, int K, int mode, const int* __restrict__ flag,
    int vcol0, unsigned short* __restrict__ vtout)
{
  __shared__ __align__(16) unsigned short As[64*64];    // 8 KB
  __shared__ __align__(16) unsigned short Bs[128*64];   // 16 KB
  int tid = threadIdx.x;
  int bm0 = blockIdx.y * 64, bn0 = blockIdx.x * 128;
  int wid = tid >> 6, lane = tid & 63;
  int wm = (wid & 1) * 32, wn = (wid >> 1) * 64;
  int fl = (mode == 3) ? flag[0] : 0;
  floatx4 acc[2][4] = {};

  // staging: 24 segments of 8 rows x 64 cols (1 KB each); wave w -> segs [6w, 6w+6)
  const unsigned short* gp[6];
  unsigned short* lp[6];
  int lrow = lane >> 3, lchunk = (lane & 7) ^ lrow;
  #pragma unroll
  for (int t = 0; t < 6; t++){
    int seg = wid * 6 + t;
    if (seg < 8){
      gp[t] = A + (size_t)(bm0 + seg*8 + lrow) * K + lchunk*8;
      lp[t] = &As[seg * 512];
    } else {
      int s = seg - 8;
      gp[t] = BT + (size_t)(bn0 + s*8 + lrow) * K + lchunk*8;
      lp[t] = &Bs[s * 512];
    }
  }

  int mrow = lane & 15, quad = lane >> 4;
  for (int kt = 0; kt < K; kt += 64){
    #pragma unroll
    for (int t = 0; t < 6; t++) gld16(gp[t] + kt, lp[t]);
    __syncthreads();   // drains vmcnt -> staged data visible
    #pragma unroll
    for (int k2 = 0; k2 < 2; k2++){
      short8 af[2], bf[4];
      #pragma unroll
      for (int i = 0; i < 2; i++){
        int r = wm + i*16 + mrow;
        int slot = (k2*4 + quad) ^ (r & 7);
        af[i] = *(const short8*)&As[r*64 + slot*8];
      }
      #pragma unroll
      for (int j = 0; j < 4; j++){
        int r = wn + j*16 + mrow;
        int slot = (k2*4 + quad) ^ (r & 7);
        bf[j] = *(const short8*)&Bs[r*64 + slot*8];
      }
      #pragma unroll
      for (int i = 0; i < 2; i++){
        #pragma unroll
        for (int j = 0; j < 4; j++){
          acc[i][j] = __builtin_amdgcn_mfma_f32_16x16x32_bf16(af[i], bf[j], acc[i][j], 0,0,0);
        }
      }
    }
    __syncthreads();   // keep next iter's staging off the in-use tiles
  }

  int colb = mrow, rowb = quad * 4;
  #pragma unroll
  for (int i=0;i<2;i++){
    #pragma unroll
    for (int j=0;j<4;j++){
      int col = bn0 + wn + j*16 + colb;
      float bv = b2f(bias[col]);
      int row0 = bm0 + wm + i*16 + rowb;
      if (mode == 4 && col >= vcol0){
        ushort4 uv;
        uv.x = f2b(acc[i][j][0] + bv);
        uv.y = f2b(acc[i][j][1] + bv);
        uv.z = f2b(acc[i][j][2] + bv);
        uv.w = f2b(acc[i][j][3] + bv);
        *(ushort4*)(vtout + (size_t)(col - vcol0)*M + row0) = uv;
      } else {
        #pragma unroll
        for (int rr=0;rr<4;rr++){
          int row = row0 + rr;
          float v = acc[i][j][rr] + bv;
          size_t off = (size_t)row*N + col;
          if      (mode == 0 || mode == 4){ outb[off] = f2b(v); }
          else if (mode == 1){ outb[off] = f2b(gelu_tanh(v)); }
          else if (mode == 2){ resid[off] += v; }
          else {
            float o = v + resid[off];
            if (fl) ((float*)outb)[off] = o;
            else    outb[off] = f2b(o);
          }
        }
      }
    }
  }
}

// ---------------- flash attention (MFMA) ----------------
template<int CA, int SCOR>
__global__ __launch_bounds__(256) void k_flash(
    const unsigned short* __restrict__ qb, int qstride,
    const unsigned short* __restrict__ kb, int kstride,
    const unsigned short* __restrict__ vt,
    const unsigned short* __restrict__ scorer,
    unsigned short* __restrict__ out)
{
  __shared__ __align__(16) unsigned short Ks[64*72];
  __shared__ __align__(16) unsigned short VTs[64*72];
  __shared__ __align__(16) unsigned short Ps[4][16*72];
  __shared__ float scs[64];
  int tid = threadIdx.x;
  int q0 = blockIdx.x * 64, h = blockIdx.y;
  int w = tid >> 6, lane = tid & 63;
  int cn = lane & 15, quad = lane >> 4, kq = quad * 8;
  unsigned short* Pw = Ps[w];
  const unsigned short* qrow = qb + (size_t)(q0 + w*16 + cn) * qstride + h*HD;
  short8 qf0 = *(const short8*)(qrow + kq);
  short8 qf1 = *(const short8*)(qrow + kq + 32);
  floatx4 oacc[4] = {};
  float m_i[4], l_i[4];
  #pragma unroll
  for (int r=0;r<4;r++){ m_i[r] = -3.0e38f; l_i[r] = 0.f; }
  int qmr = q0 + w*16 + quad*4;
  int sr = tid >> 2, sc2 = (tid & 3) * 16;
  int klmax = q0 + 64 + CA; if (klmax > S) klmax = S;
  for (int kc = 0; kc < klmax; kc += 64){
    __syncthreads();
    {
      const unsigned short* kp = kb + (size_t)(kc + sr) * kstride + h*HD + sc2;
      uint4 a0 = *(const uint4*)kp;
      uint4 a1 = *(const uint4*)(kp + 8);
      const unsigned short* vp = vt + (size_t)(h*HD + sr) * S + kc + sc2;
      uint4 b0 = *(const uint4*)vp;
      uint4 b1 = *(const uint4*)(vp + 8);
      *(uint4*)&Ks[sr*72 + sc2]      = a0;
      *(uint4*)&Ks[sr*72 + sc2 + 8]  = a1;
      *(uint4*)&VTs[sr*72 + sc2]     = b0;
      *(uint4*)&VTs[sr*72 + sc2 + 8] = b1;
      if (SCOR && tid < 64) scs[tid] = b2f(scorer[kc + tid]);
    }
    __syncthreads();
    floatx4 sv[4] = {};
    #pragma unroll
    for (int t=0;t<4;t++){
      short8 b0 = *(const short8*)&Ks[(t*16 + cn)*72 + kq];
      short8 b1 = *(const short8*)&Ks[(t*16 + cn)*72 + kq + 32];
      sv[t] = __builtin_amdgcn_mfma_f32_16x16x32_bf16(qf0, b0, sv[t], 0,0,0);
      sv[t] = __builtin_amdgcn_mfma_f32_16x16x32_bf16(qf1, b1, sv[t], 0,0,0);
    }
    #pragma unroll
    for (int r=0;r<4;r++){
      int qlim = qmr + r + CA;
      float mx = -3.0e38f;
      float pv[4];
      #pragma unroll
      for (int t=0;t<4;t++){
        int kn = kc + t*16 + cn;
        float s = sv[t][r] * 0.125f;
        if (SCOR) s += scs[t*16 + cn];
        s = (kn <= qlim) ? s : -3.0e38f;
        pv[t] = s;
        mx = fmaxf(mx, s);
      }
      mx = fmaxf(mx, __shfl_xor(mx,1,64));
      mx = fmaxf(mx, __shfl_xor(mx,2,64));
      mx = fmaxf(mx, __shfl_xor(mx,4,64));
      mx = fmaxf(mx, __shfl_xor(mx,8,64));
      float mnew = fmaxf(m_i[r], mx);
      float al = __expf(m_i[r] - mnew);
      m_i[r] = mnew;
      float sum = 0.f;
      #pragma unroll
      for (int t=0;t<4;t++){
        float e = __expf(pv[t] - mnew);
        sum += e;
        Pw[(quad*4 + r)*72 + t*16 + cn] = f2b(e);
      }
      sum += __shfl_xor(sum,1,64);
      sum += __shfl_xor(sum,2,64);
      sum += __shfl_xor(sum,4,64);
      sum += __shfl_xor(sum,8,64);
      l_i[r] = l_i[r]*al + sum;
      #pragma unroll
      for (int t2=0;t2<4;t2++) oacc[t2][r] *= al;
    }
    short8 pf0 = *(const short8*)&Pw[cn*72 + kq];
    short8 pf1 = *(const short8*)&Pw[cn*72 + kq + 32];
    #pragma unroll
    for (int t2=0;t2<4;t2++){
      short8 v0 = *(const short8*)&VTs[(t2*16 + cn)*72 + kq];
      short8 v1 = *(const short8*)&VTs[(t2*16 + cn)*72 + kq + 32];
      oacc[t2] = __builtin_amdgcn_mfma_f32_16x16x32_bf16(pf0, v0, oacc[t2], 0,0,0);
      oacc[t2] = __builtin_amdgcn_mfma_f32_16x16x32_bf16(pf1, v1, oacc[t2], 0,0,0);
    }
  }
  #pragma unroll
  for (int r=0;r<4;r++){
    float inv = 1.0f / l_i[r];
    size_t rowoff = (size_t)(qmr + r) * H + h*HD;
    #pragma unroll
    for (int t2=0;t2<4;t2++)
      out[rowoff + t2*16 + cn] = f2b(oacc[t2][r] * inv);
  }
}

extern "C" void kernel_launch(void* const* d_in, const int* in_sizes, int n_in,
                              void* d_out, int out_size, void* d_ws, size_t ws_size,
                              hipStream_t stream)
{
  const void* hs          = d_in[0];
  const void* enc         = d_in[1];
  const void* scorer      = d_in[2];
  const void* ln1_g       = d_in[3];
  const void* ln1_b       = d_in[4];
  const void* c_attn_w    = d_in[5];
  const void* c_attn_b    = d_in[6];
  const void* attn_proj_w = d_in[7];
  const void* attn_proj_b = d_in[8];
  const void* lnx_g       = d_in[9];
  const void* lnx_b       = d_in[10];
  const void* q_attn_w    = d_in[11];
  const void* q_attn_b    = d_in[12];
  const void* x_kv_w      = d_in[13];
  const void* x_kv_b      = d_in[14];
  const void* x_proj_w    = d_in[15];
  const void* x_proj_b    = d_in[16];
  const void* ln2_g       = d_in[17];
  const void* ln2_b       = d_in[18];
  const void* fc_w        = d_in[19];
  const void* fc_b        = d_in[20];
  const void* mlp_proj_w  = d_in[21];
  const void* mlp_proj_b  = d_in[22];
  unsigned short* out = (unsigned short*)d_out;

  char* ws = (char*)d_ws; size_t off = 0;
  auto alloc = [&](size_t bytes)->void*{
    void* p = ws + off; off += (bytes + 255) & ~(size_t)255; return p;
  };
  unsigned short* wT_cattn = (unsigned short*)alloc((size_t)3072*1024*2);
  unsigned short* wT_aproj = (unsigned short*)alloc((size_t)1024*1024*2);
  unsigned short* wT_qattn = (unsigned short*)alloc((size_t)1024*1024*2);
  unsigned short* wT_xkv   = (unsigned short*)alloc((size_t)2048*1024*2);
  unsigned short* wT_xproj = (unsigned short*)alloc((size_t)1024*1024*2);
  unsigned short* wT_fc    = (unsigned short*)alloc((size_t)4096*1024*2);
  unsigned short* wT_mlp   = (unsigned short*)alloc((size_t)1024*4096*2);
  unsigned short* enc_c    = (unsigned short*)alloc((size_t)SEQE*H*2);
  unsigned short* canon    = (unsigned short*)alloc((size_t)32768*2);
  unsigned short* xln      = (unsigned short*)alloc((size_t)S*H*2);
  unsigned short* qkv      = (unsigned short*)alloc((size_t)S*3*H*2);
  unsigned short* attnout  = (unsigned short*)alloc((size_t)S*H*2);
  unsigned short* q2       = (unsigned short*)alloc((size_t)S*H*2);
  unsigned short* kvbuf    = (unsigned short*)alloc((size_t)SEQE*2*H*2);
  unsigned short* vt_self  = (unsigned short*)alloc((size_t)H*S*2);
  unsigned short* vt_cross = (unsigned short*)alloc((size_t)H*SEQE*2);
  unsigned short* fcbuf    = (unsigned short*)alloc((size_t)S*INNER*2);
  float*          hidden   = (float*)alloc((size_t)S*H*4);
  int*            flag     = (int*)alloc(256);

  unsigned short* p = canon;
  auto carve = [&](int n)->unsigned short*{ unsigned short* q = p; p += n; return q; };
  unsigned short* c_ln1g = carve(1024); unsigned short* c_ln1b = carve(1024);
  unsigned short* c_catb = carve(3072); unsigned short* c_aprb = carve(1024);
  unsigned short* c_lnxg = carve(1024); unsigned short* c_lnxb = carve(1024);
  unsigned short* c_qatb = carve(1024); unsigned short* c_xkvb = carve(2048);
  unsigned short* c_xprb = carve(1024); unsigned short* c_ln2g = carve(1024);
  unsigned short* c_ln2b = carve(1024); unsigned short* c_fcb  = carve(4096);
  unsigned short* c_mlpb = carve(1024); unsigned short* c_scor = carve(2048);

  // 1. dtype sniff
  k_sniff<<<1, 256, 0, stream>>>((const unsigned short*)hs, flag);

  // 2. residual init (fp32)
  k_resid_init<<<(S*H)/256, 256, 0, stream>>>(hs, hidden, S*H, flag);

  // 3. weight transposes
  dim3 tb(32,8);
  k_transpose<<<dim3(3072/32,1024/32), tb, 0, stream>>>(c_attn_w,    wT_cattn, 1024, 3072, flag);
  k_transpose<<<dim3(1024/32,1024/32), tb, 0, stream>>>(attn_proj_w, wT_aproj, 1024, 1024, flag);
  k_transpose<<<dim3(1024/32,1024/32), tb, 0, stream>>>(q_attn_w,    wT_qattn, 1024, 1024, flag);
  k_transpose<<<dim3(2048/32,1024/32), tb, 0, stream>>>(x_kv_w,      wT_xkv,   1024, 2048, flag);
  k_transpose<<<dim3(1024/32,1024/32), tb, 0, stream>>>(x_proj_w,    wT_xproj, 1024, 1024, flag);
  k_transpose<<<dim3(4096/32,1024/32), tb, 0, stream>>>(fc_w,        wT_fc,    1024, 4096, flag);
  k_transpose<<<dim3(1024/32,4096/32), tb, 0, stream>>>(mlp_proj_w,  wT_mlp,   4096, 1024, flag);

  // 4. canonicalize encoder states + small params
  k_cvt<<<(SEQE*H)/256, 256, 0, stream>>>(enc, enc_c, SEQE*H, flag);
  SmallCvt sc{};
  const void* ssrc[14] = {ln1_g, ln1_b, c_attn_b, attn_proj_b, lnx_g, lnx_b,
                          q_attn_b, x_kv_b, x_proj_b, ln2_g, ln2_b, fc_b,
                          mlp_proj_b, scorer};
  unsigned short* sdst[14] = {c_ln1g, c_ln1b, c_catb, c_aprb, c_lnxg, c_lnxb,
                              c_qatb, c_xkvb, c_xprb, c_ln2g, c_ln2b, c_fcb,
                              c_mlpb, c_scor};
  int sn[14] = {1024,1024,3072,1024,1024,1024,1024,2048,1024,1024,1024,4096,1024,2048};
  for (int i=0;i<14;i++){ sc.src[i]=ssrc[i]; sc.dst[i]=sdst[i]; sc.n[i]=sn[i]; }
  k_cvt_small<<<14, 256, 0, stream>>>(sc, flag);

  // --- self attention ---
  k_layernorm<<<S, 256, 0, stream>>>(hidden, c_ln1g, c_ln1b, xln);
  k_gemm64<<<dim3(3072/128, S/64), 256, 0, stream>>>(xln, wT_cattn, c_catb,
      qkv, nullptr, S, 3072, 1024, 4, flag, 2048, vt_self);
  k_flash<0,0><<<dim3(S/64, NHEAD), 256, 0, stream>>>(
      qkv, 3*H, qkv + 1024, 3*H, vt_self, nullptr, attnout);
  k_gemm64<<<dim3(1024/128, S/64), 256, 0, stream>>>(attnout, wT_aproj, c_aprb,
      nullptr, hidden, S, 1024, 1024, 2, flag, 0, nullptr);

  // --- cross attention ---
  k_layernorm<<<S, 256, 0, stream>>>(hidden, c_lnxg, c_lnxb, xln);
  k_gemm64<<<dim3(1024/128, S/64), 256, 0, stream>>>(xln, wT_qattn, c_qatb,
      q2, nullptr, S, 1024, 1024, 0, flag, 0, nullptr);
  k_gemm64<<<dim3(2048/128, SEQE/64), 256, 0, stream>>>(enc_c, wT_xkv, c_xkvb,
      kvbuf, nullptr, SEQE, 2048, 1024, 4, flag, 1024, vt_cross);
  k_flash<2,1><<<dim3(S/64, NHEAD), 256, 0, stream>>>(
      q2, H, kvbuf, 2*H, vt_cross, c_scor, attnout);
  k_gemm64<<<dim3(1024/128, S/64), 256, 0, stream>>>(attnout, wT_xproj, c_xprb,
      nullptr, hidden, S, 1024, 1024, 2, flag, 0, nullptr);

  // --- MLP ---
  k_layernorm<<<S, 256, 0, stream>>>(hidden, c_ln2g, c_ln2b, xln);
  k_gemm64<<<dim3(INNER/128, S/64), 256, 0, stream>>>(xln, wT_fc, c_fcb,
      fcbuf, nullptr, S, INNER, 1024, 1, flag, 0, nullptr);
  k_gemm64<<<dim3(1024/128, S/64), 256, 0, stream>>>(fcbuf, wT_mlp, c_mlpb,
      out, hidden, S, 1024, INNER, 3, flag, 0, nullptr);
}

// Round 5
// 546.827 us; speedup vs baseline: 2.3828x; 1.0327x over previous
//
#include <hip/hip_runtime.h>
#include <stdint.h>

#define H     1024
#define S     2048
#define SEQE  2048
#define NHEAD 16
#define HD    64
#define INNER 4096
#define EPSLN 1e-5f
#define LOG2E 1.44269504089f
#define SCALE2 (0.125f * LOG2E)

typedef __attribute__((ext_vector_type(8))) short short8;
typedef __attribute__((ext_vector_type(4))) float floatx4;

__device__ __forceinline__ float b2f(unsigned short u){
  union { unsigned int i; float f; } v; v.i = ((unsigned int)u) << 16; return v.f;
}
__device__ __forceinline__ unsigned short f2b(float f){
  union { float f; unsigned int i; } v; v.f = f;
  unsigned int x = v.i;
  unsigned int r = (x + 0x7FFFu + ((x >> 16) & 1u)) >> 16;
  return (unsigned short)r;
}
__device__ __forceinline__ float gelu_tanh(float x){
  float x3 = x*x*x;
  float t = tanhf(0.7978845608028654f*(x + 0.044715f*x3));
  return 0.5f*x*(1.0f+t);
}

// async global->LDS, 16B per lane; LDS dest = wave-uniform base + lane*16
__device__ __forceinline__ void gld16(const unsigned short* g, unsigned short* l){
  __builtin_amdgcn_global_load_lds(
      (const __attribute__((address_space(1))) unsigned int*)g,
      (__attribute__((address_space(3))) unsigned int*)l,
      16, 0, 0);
}

// ---------------- dtype sniff ----------------
__global__ __launch_bounds__(256) void k_sniff(
    const unsigned short* __restrict__ p, int* __restrict__ flag){
  __shared__ int any;
  if (threadIdx.x == 0) any = 0;
  __syncthreads();
  int bad = 0;
  for (int i = threadIdx.x; i < 8192; i += 256){
    float v = b2f(p[i]);
    if (!(fabsf(v) < 1e6f)) bad = 1;
  }
  if (bad) any = 1;
  __syncthreads();
  if (threadIdx.x == 0) flag[0] = any;
}

// ---------------- flag-aware convert -> bf16 ----------------
__global__ __launch_bounds__(256) void k_cvt(
    const void* __restrict__ src, unsigned short* __restrict__ dst, int n,
    const int* __restrict__ flag){
  int i = blockIdx.x * 256 + threadIdx.x;
  if (i < n)
    dst[i] = flag[0] ? f2b(((const float*)src)[i]) : ((const unsigned short*)src)[i];
}

struct SmallCvt {
  const void* src[16];
  unsigned short* dst[16];
  int n[16];
};
__global__ __launch_bounds__(256) void k_cvt_small(SmallCvt sc, const int* __restrict__ flag){
  int t = blockIdx.x;
  int fl = flag[0];
  const float* sf = (const float*)sc.src[t];
  const unsigned short* sb = (const unsigned short*)sc.src[t];
  unsigned short* d = sc.dst[t];
  for (int i = threadIdx.x; i < sc.n[t]; i += 256)
    d[i] = fl ? f2b(sf[i]) : sb[i];
}

// ---------------- transpose W[R][C] -> WT[C][R] ----------------
__global__ __launch_bounds__(256) void k_transpose(
    const void* __restrict__ srcv, unsigned short* __restrict__ dst,
    int R, int C, const int* __restrict__ flag){
  __shared__ unsigned short t[32][33];
  const float* sf = (const float*)srcv;
  const unsigned short* sb = (const unsigned short*)srcv;
  int fl = flag[0];
  int bc = blockIdx.x * 32, br = blockIdx.y * 32;
  int tx = threadIdx.x, ty = threadIdx.y;
  #pragma unroll
  for (int i = 0; i < 4; i++){
    size_t idx = (size_t)(br + ty + i*8) * C + bc + tx;
    t[ty + i*8][tx] = fl ? f2b(sf[idx]) : sb[idx];
  }
  __syncthreads();
  #pragma unroll
  for (int i = 0; i < 4; i++)
    dst[(size_t)(bc + ty + i*8) * R + br + tx] = t[tx][ty + i*8];
}

// ---------------- residual init ----------------
__global__ __launch_bounds__(256) void k_resid_init(
    const void* __restrict__ in, float* __restrict__ out, int n,
    const int* __restrict__ flag){
  int i = blockIdx.x * 256 + threadIdx.x;
  if (i < n)
    out[i] = flag[0] ? ((const float*)in)[i] : b2f(((const unsigned short*)in)[i]);
}

// ---------------- LayerNorm ----------------
__global__ __launch_bounds__(256) void k_layernorm(
    const float* __restrict__ x,
    const unsigned short* __restrict__ g, const unsigned short* __restrict__ bb,
    unsigned short* __restrict__ y){
  __shared__ float scratch[4];
  int row = blockIdx.x, tid = threadIdx.x;
  float v[4];
  #pragma unroll
  for (int i=0;i<4;i++) v[i] = x[(size_t)row*H + tid + i*256];
  float s = v[0]+v[1]+v[2]+v[3];
  for (int o=32;o;o>>=1) s += __shfl_xor(s,o,64);
  int wid = tid>>6, lane = tid&63;
  if (lane==0) scratch[wid]=s;
  __syncthreads();
  float mu = (scratch[0]+scratch[1]+scratch[2]+scratch[3]) * (1.0f/H);
  __syncthreads();
  float q = 0.f;
  #pragma unroll
  for (int i=0;i<4;i++){ float d=v[i]-mu; q += d*d; }
  for (int o=32;o;o>>=1) q += __shfl_xor(q,o,64);
  if (lane==0) scratch[wid]=q;
  __syncthreads();
  float var = (scratch[0]+scratch[1]+scratch[2]+scratch[3]) * (1.0f/H);
  float rstd = rsqrtf(var + EPSLN);
  #pragma unroll
  for (int i=0;i<4;i++){
    int idx = tid + i*256;
    float o = (v[i]-mu)*rstd*b2f(g[idx]) + b2f(bb[idx]);
    y[(size_t)row*H + idx] = f2b(o);
  }
}

// ---------------- bf16 MFMA GEMM, 64x128 tile, BK=64, async LDS staging ----------------
__global__ __launch_bounds__(256) void k_gemm64(
    const unsigned short* __restrict__ A, const unsigned short* __restrict__ BT,
    const unsigned short* __restrict__ bias,
    unsigned short* __restrict__ outb, float* __restrict__ resid,
    int M, int N, int K, int mode, const int* __restrict__ flag,
    int vcol0, unsigned short* __restrict__ vtout)
{
  __shared__ __align__(16) unsigned short As[64*64];
  __shared__ __align__(16) unsigned short Bs[128*64];
  int tid = threadIdx.x;
  int bm0 = blockIdx.y * 64, bn0 = blockIdx.x * 128;
  int wid = tid >> 6, lane = tid & 63;
  int wm = (wid & 1) * 32, wn = (wid >> 1) * 64;
  int fl = (mode == 3) ? flag[0] : 0;
  floatx4 acc[2][4] = {};

  const unsigned short* gp[6];
  unsigned short* lp[6];
  int lrow = lane >> 3, lchunk = (lane & 7) ^ lrow;
  #pragma unroll
  for (int t = 0; t < 6; t++){
    int seg = wid * 6 + t;
    if (seg < 8){
      gp[t] = A + (size_t)(bm0 + seg*8 + lrow) * K + lchunk*8;
      lp[t] = &As[seg * 512];
    } else {
      int s = seg - 8;
      gp[t] = BT + (size_t)(bn0 + s*8 + lrow) * K + lchunk*8;
      lp[t] = &Bs[s * 512];
    }
  }

  int mrow = lane & 15, quad = lane >> 4;
  for (int kt = 0; kt < K; kt += 64){
    #pragma unroll
    for (int t = 0; t < 6; t++) gld16(gp[t] + kt, lp[t]);
    __syncthreads();
    #pragma unroll
    for (int k2 = 0; k2 < 2; k2++){
      short8 af[2], bf[4];
      #pragma unroll
      for (int i = 0; i < 2; i++){
        int r = wm + i*16 + mrow;
        int slot = (k2*4 + quad) ^ (r & 7);
        af[i] = *(const short8*)&As[r*64 + slot*8];
      }
      #pragma unroll
      for (int j = 0; j < 4; j++){
        int r = wn + j*16 + mrow;
        int slot = (k2*4 + quad) ^ (r & 7);
        bf[j] = *(const short8*)&Bs[r*64 + slot*8];
      }
      #pragma unroll
      for (int i = 0; i < 2; i++){
        #pragma unroll
        for (int j = 0; j < 4; j++){
          acc[i][j] = __builtin_amdgcn_mfma_f32_16x16x32_bf16(af[i], bf[j], acc[i][j], 0,0,0);
        }
      }
    }
    __syncthreads();
  }

  int colb = mrow, rowb = quad * 4;
  #pragma unroll
  for (int i=0;i<2;i++){
    #pragma unroll
    for (int j=0;j<4;j++){
      int col = bn0 + wn + j*16 + colb;
      float bv = b2f(bias[col]);
      int row0 = bm0 + wm + i*16 + rowb;
      if (mode == 4 && col >= vcol0){
        ushort4 uv;
        uv.x = f2b(acc[i][j][0] + bv);
        uv.y = f2b(acc[i][j][1] + bv);
        uv.z = f2b(acc[i][j][2] + bv);
        uv.w = f2b(acc[i][j][3] + bv);
        *(ushort4*)(vtout + (size_t)(col - vcol0)*M + row0) = uv;
      } else {
        #pragma unroll
        for (int rr=0;rr<4;rr++){
          int row = row0 + rr;
          float v = acc[i][j][rr] + bv;
          size_t off = (size_t)row*N + col;
          if      (mode == 0 || mode == 4){ outb[off] = f2b(v); }
          else if (mode == 1){ outb[off] = f2b(gelu_tanh(v)); }
          else if (mode == 2){ resid[off] += v; }
          else {
            float o = v + resid[off];
            if (fl) ((float*)outb)[off] = o;
            else    outb[off] = f2b(o);
          }
        }
      }
    }
  }
}

// ---------------- split-K flash attention (MFMA, exp2 domain, partials) ----------------
// grid (32 qtiles, NHEAD, 4 splits); each active block: 8-chunk (512-key) segment.
// Partials: obuf[pidx][row64][d] bf16 unnormalized O; mlbuf[pidx][row64]{m,l} fp32.
template<int CA, int SCOR>
__global__ __launch_bounds__(256) void k_flash2(
    const unsigned short* __restrict__ qb, int qstride,
    const unsigned short* __restrict__ kb, int kstride,
    const unsigned short* __restrict__ vt,
    const unsigned short* __restrict__ scorer,
    unsigned short* __restrict__ obuf, float* __restrict__ mlbuf, int TOTS)
{
  int t = blockIdx.x, h = blockIdx.y, sp = blockIdx.z;
  int klmax0 = 64*t + 64 + CA; if (klmax0 > S) klmax0 = S;
  int nch = (klmax0 + 63) >> 6;
  int nsp = (nch + 7) >> 3;
  if (sp >= nsp) return;
  int base = 0;
  for (int i = 0; i < t; i++){
    int km = 64*i + 64 + CA; if (km > S) km = S;
    base += (((km + 63) >> 6) + 7) >> 3;
  }
  int pidx = h*TOTS + base + sp;
  int c0 = sp*8, c1 = c0 + 8; if (c1 > nch) c1 = nch;

  __shared__ __align__(16) unsigned short Ks[64*64];
  __shared__ __align__(16) unsigned short VTs[64*64];
  __shared__ __align__(16) unsigned short Ps[4][16*72];
  __shared__ float scs[64];
  int tid = threadIdx.x;
  int q0 = t*64;
  int w = tid >> 6, lane = tid & 63;
  int cn = lane & 15, quad = lane >> 4, kq = quad * 8;
  unsigned short* Pw = Ps[w];
  int srow0 = w*16;
  int lr = lane >> 3;
  int lc = ((lane & 7) ^ lr) * 8;
  const unsigned short* kg0 = kb + (size_t)(srow0 + lr) * kstride + h*HD + lc;
  const unsigned short* kg1 = kb + (size_t)(srow0 + 8 + lr) * kstride + h*HD + lc;
  const unsigned short* vg0 = vt + (size_t)(h*HD + srow0 + lr) * S + lc;
  const unsigned short* vg1 = vt + (size_t)(h*HD + srow0 + 8 + lr) * S + lc;
  unsigned short* kl0 = &Ks[srow0 * 64];
  unsigned short* kl1 = &Ks[(srow0 + 8) * 64];
  unsigned short* vl0 = &VTs[srow0 * 64];
  unsigned short* vl1 = &VTs[(srow0 + 8) * 64];

  const unsigned short* qrow = qb + (size_t)(q0 + w*16 + cn) * qstride + h*HD;
  short8 qf0 = *(const short8*)(qrow + kq);
  short8 qf1 = *(const short8*)(qrow + kq + 32);
  floatx4 oacc[4] = {};
  float l_lane[4] = {0,0,0,0};
  float m_w = -1.0e38f;
  int qmr = q0 + w*16 + quad*4;

  for (int ci = c0; ci < c1; ci++){
    int kc = ci * 64;
    __syncthreads();
    gld16(kg0 + (size_t)kc * kstride, kl0);
    gld16(kg1 + (size_t)kc * kstride, kl1);
    gld16(vg0 + kc, vl0);
    gld16(vg1 + kc, vl1);
    if (SCOR && tid < 64) scs[tid] = b2f(scorer[kc + tid]) * LOG2E;
    __syncthreads();

    floatx4 sv[4] = {};
    #pragma unroll
    for (int t4=0;t4<4;t4++){
      int rr = t4*16 + cn;
      int s0 = ((quad    ) ^ (rr & 7)) * 8;
      int s1 = ((quad + 4) ^ (rr & 7)) * 8;
      short8 b0 = *(const short8*)&Ks[rr*64 + s0];
      short8 b1 = *(const short8*)&Ks[rr*64 + s1];
      sv[t4] = __builtin_amdgcn_mfma_f32_16x16x32_bf16(qf0, b0, sv[t4], 0,0,0);
      sv[t4] = __builtin_amdgcn_mfma_f32_16x16x32_bf16(qf1, b1, sv[t4], 0,0,0);
    }

    float vals[16];
    float lmax = -1.0e38f;
    bool needmask = (kc + 63 > q0 + w*16 + CA);
    #pragma unroll
    for (int t4=0;t4<4;t4++){
      #pragma unroll
      for (int r=0;r<4;r++){
        float s = sv[t4][r] * SCALE2;
        if (SCOR) s += scs[t4*16 + cn];
        if (needmask){
          int kn = kc + t4*16 + cn;
          s = (kn <= qmr + r + CA) ? s : -1.0e38f;
        }
        vals[t4*4+r] = s;
        lmax = fmaxf(lmax, s);
      }
    }
    #pragma unroll
    for (int o=1;o<64;o<<=1) lmax = fmaxf(lmax, __shfl_xor(lmax, o, 64));
    if (lmax > m_w){
      float al = exp2f(m_w - lmax);
      m_w = lmax;
      #pragma unroll
      for (int r=0;r<4;r++) l_lane[r] *= al;
      #pragma unroll
      for (int t2=0;t2<4;t2++){
        #pragma unroll
        for (int r=0;r<4;r++) oacc[t2][r] *= al;
      }
    }
    #pragma unroll
    for (int t4=0;t4<4;t4++){
      #pragma unroll
      for (int r=0;r<4;r++){
        float e = exp2f(vals[t4*4+r] - m_w);
        l_lane[r] += e;
        Pw[(quad*4+r)*72 + t4*16 + cn] = f2b(e);
      }
    }
    short8 pf0 = *(const short8*)&Pw[cn*72 + kq];
    short8 pf1 = *(const short8*)&Pw[cn*72 + kq + 32];
    #pragma unroll
    for (int t2=0;t2<4;t2++){
      int rr = t2*16 + cn;
      int s0 = ((quad    ) ^ (rr & 7)) * 8;
      int s1 = ((quad + 4) ^ (rr & 7)) * 8;
      short8 v0 = *(const short8*)&VTs[rr*64 + s0];
      short8 v1 = *(const short8*)&VTs[rr*64 + s1];
      oacc[t2] = __builtin_amdgcn_mfma_f32_16x16x32_bf16(pf0, v0, oacc[t2], 0,0,0);
      oacc[t2] = __builtin_amdgcn_mfma_f32_16x16x32_bf16(pf1, v1, oacc[t2], 0,0,0);
    }
  }

  float lrow[4];
  #pragma unroll
  for (int r=0;r<4;r++){
    float l = l_lane[r];
    l += __shfl_xor(l,1,64); l += __shfl_xor(l,2,64);
    l += __shfl_xor(l,4,64); l += __shfl_xor(l,8,64);
    lrow[r] = l;
  }
  size_t ob = (size_t)pidx*4096 + (size_t)(w*16 + quad*4)*64;
  #pragma unroll
  for (int t2=0;t2<4;t2++){
    #pragma unroll
    for (int r=0;r<4;r++)
      obuf[ob + r*64 + t2*16 + cn] = f2b(oacc[t2][r]);
  }
  if (cn == 0){
    #pragma unroll
    for (int r=0;r<4;r++){
      int row64 = w*16 + quad*4 + r;
      mlbuf[((size_t)pidx*64 + row64)*2]   = m_w;
      mlbuf[((size_t)pidx*64 + row64)*2+1] = lrow[r];
    }
  }
}

// ---------------- split-K combine ----------------
template<int CA>
__global__ __launch_bounds__(256) void k_comb(
    const unsigned short* __restrict__ obuf, const float* __restrict__ mlbuf,
    unsigned short* __restrict__ out, int TOTS)
{
  int h = blockIdx.y;
  int row = blockIdx.x*16 + (threadIdx.x >> 4);
  int d0 = (threadIdx.x & 15) * 4;
  int t = row >> 6;
  int klmax0 = 64*t + 64 + CA; if (klmax0 > S) klmax0 = S;
  int nch = (klmax0 + 63) >> 6;
  int nsp = (nch + 7) >> 3;
  int base = 0;
  for (int i = 0; i < t; i++){
    int km = 64*i + 64 + CA; if (km > S) km = S;
    base += (((km + 63) >> 6) + 7) >> 3;
  }
  int row64 = row & 63;
  float mp[4], lp[4];
  float M = -1.0e38f;
  for (int p = 0; p < nsp; p++){
    int pi = h*TOTS + base + p;
    mp[p] = mlbuf[((size_t)pi*64 + row64)*2];
    lp[p] = mlbuf[((size_t)pi*64 + row64)*2+1];
    M = fmaxf(M, mp[p]);
  }
  float L = 0.f;
  float o0=0.f,o1=0.f,o2=0.f,o3=0.f;
  for (int p = 0; p < nsp; p++){
    int pi = h*TOTS + base + p;
    float wgt = exp2f(mp[p] - M);
    L += lp[p]*wgt;
    const unsigned short* op = obuf + (size_t)pi*4096 + row64*64 + d0;
    o0 += b2f(op[0])*wgt; o1 += b2f(op[1])*wgt;
    o2 += b2f(op[2])*wgt; o3 += b2f(op[3])*wgt;
  }
  float inv = 1.0f / L;
  size_t oo = (size_t)row*H + h*HD + d0;
  out[oo]   = f2b(o0*inv); out[oo+1] = f2b(o1*inv);
  out[oo+2] = f2b(o2*inv); out[oo+3] = f2b(o3*inv);
}

extern "C" void kernel_launch(void* const* d_in, const int* in_sizes, int n_in,
                              void* d_out, int out_size, void* d_ws, size_t ws_size,
                              hipStream_t stream)
{
  const void* hs          = d_in[0];
  const void* enc         = d_in[1];
  const void* scorer      = d_in[2];
  const void* ln1_g       = d_in[3];
  const void* ln1_b       = d_in[4];
  const void* c_attn_w    = d_in[5];
  const void* c_attn_b    = d_in[6];
  const void* attn_proj_w = d_in[7];
  const void* attn_proj_b = d_in[8];
  const void* lnx_g       = d_in[9];
  const void* lnx_b       = d_in[10];
  const void* q_attn_w    = d_in[11];
  const void* q_attn_b    = d_in[12];
  const void* x_kv_w      = d_in[13];
  const void* x_kv_b      = d_in[14];
  const void* x_proj_w    = d_in[15];
  const void* x_proj_b    = d_in[16];
  const void* ln2_g       = d_in[17];
  const void* ln2_b       = d_in[18];
  const void* fc_w        = d_in[19];
  const void* fc_b        = d_in[20];
  const void* mlp_proj_w  = d_in[21];
  const void* mlp_proj_b  = d_in[22];
  unsigned short* out = (unsigned short*)d_out;

  char* ws = (char*)d_ws; size_t off = 0;
  auto alloc = [&](size_t bytes)->void*{
    void* p = ws + off; off += (bytes + 255) & ~(size_t)255; return p;
  };
  unsigned short* wT_cattn = (unsigned short*)alloc((size_t)3072*1024*2);
  unsigned short* wT_aproj = (unsigned short*)alloc((size_t)1024*1024*2);
  unsigned short* wT_qattn = (unsigned short*)alloc((size_t)1024*1024*2);
  unsigned short* wT_xkv   = (unsigned short*)alloc((size_t)2048*1024*2);
  unsigned short* wT_xproj = (unsigned short*)alloc((size_t)1024*1024*2);
  unsigned short* wT_fc    = (unsigned short*)alloc((size_t)4096*1024*2);
  unsigned short* wT_mlp   = (unsigned short*)alloc((size_t)1024*4096*2);
  unsigned short* enc_c    = (unsigned short*)alloc((size_t)SEQE*H*2);
  unsigned short* canon    = (unsigned short*)alloc((size_t)32768*2);
  unsigned short* xln      = (unsigned short*)alloc((size_t)S*H*2);
  unsigned short* qkv      = (unsigned short*)alloc((size_t)S*3*H*2);
  unsigned short* attnout  = (unsigned short*)alloc((size_t)S*H*2);
  unsigned short* q2       = (unsigned short*)alloc((size_t)S*H*2);
  unsigned short* kvbuf    = (unsigned short*)alloc((size_t)SEQE*2*H*2);
  unsigned short* vt_self  = (unsigned short*)alloc((size_t)H*S*2);
  unsigned short* vt_cross = (unsigned short*)alloc((size_t)H*SEQE*2);
  unsigned short* fcbuf    = (unsigned short*)alloc((size_t)S*INNER*2);
  float*          hidden   = (float*)alloc((size_t)S*H*4);
  int*            flag     = (int*)alloc(256);

  // flash partials aliased into fcbuf (fcbuf only used in MLP phase):
  // obuf: 16 heads * 83 max-splits * 4096 bf16 = 5,439,488 shorts (10.88 MB)
  // mlbuf: 16*83*64*2 fp32 = 679,936 B; total 11.56 MB <= 16.78 MB fcbuf
  unsigned short* obuf  = fcbuf;
  float*          mlbuf = (float*)(fcbuf + (size_t)16*83*4096);

  unsigned short* p = canon;
  auto carve = [&](int n)->unsigned short*{ unsigned short* q = p; p += n; return q; };
  unsigned short* c_ln1g = carve(1024); unsigned short* c_ln1b = carve(1024);
  unsigned short* c_catb = carve(3072); unsigned short* c_aprb = carve(1024);
  unsigned short* c_lnxg = carve(1024); unsigned short* c_lnxb = carve(1024);
  unsigned short* c_qatb = carve(1024); unsigned short* c_xkvb = carve(2048);
  unsigned short* c_xprb = carve(1024); unsigned short* c_ln2g = carve(1024);
  unsigned short* c_ln2b = carve(1024); unsigned short* c_fcb  = carve(4096);
  unsigned short* c_mlpb = carve(1024); unsigned short* c_scor = carve(2048);

  k_sniff<<<1, 256, 0, stream>>>((const unsigned short*)hs, flag);
  k_resid_init<<<(S*H)/256, 256, 0, stream>>>(hs, hidden, S*H, flag);

  dim3 tb(32,8);
  k_transpose<<<dim3(3072/32,1024/32), tb, 0, stream>>>(c_attn_w,    wT_cattn, 1024, 3072, flag);
  k_transpose<<<dim3(1024/32,1024/32), tb, 0, stream>>>(attn_proj_w, wT_aproj, 1024, 1024, flag);
  k_transpose<<<dim3(1024/32,1024/32), tb, 0, stream>>>(q_attn_w,    wT_qattn, 1024, 1024, flag);
  k_transpose<<<dim3(2048/32,1024/32), tb, 0, stream>>>(x_kv_w,      wT_xkv,   1024, 2048, flag);
  k_transpose<<<dim3(1024/32,1024/32), tb, 0, stream>>>(x_proj_w,    wT_xproj, 1024, 1024, flag);
  k_transpose<<<dim3(4096/32,1024/32), tb, 0, stream>>>(fc_w,        wT_fc,    1024, 4096, flag);
  k_transpose<<<dim3(1024/32,4096/32), tb, 0, stream>>>(mlp_proj_w,  wT_mlp,   4096, 1024, flag);

  k_cvt<<<(SEQE*H)/256, 256, 0, stream>>>(enc, enc_c, SEQE*H, flag);
  SmallCvt sc{};
  const void* ssrc[14] = {ln1_g, ln1_b, c_attn_b, attn_proj_b, lnx_g, lnx_b,
                          q_attn_b, x_kv_b, x_proj_b, ln2_g, ln2_b, fc_b,
                          mlp_proj_b, scorer};
  unsigned short* sdst[14] = {c_ln1g, c_ln1b, c_catb, c_aprb, c_lnxg, c_lnxb,
                              c_qatb, c_xkvb, c_xprb, c_ln2g, c_ln2b, c_fcb,
                              c_mlpb, c_scor};
  int sn[14] = {1024,1024,3072,1024,1024,1024,1024,2048,1024,1024,1024,4096,1024,2048};
  for (int i=0;i<14;i++){ sc.src[i]=ssrc[i]; sc.dst[i]=sdst[i]; sc.n[i]=sn[i]; }
  k_cvt_small<<<14, 256, 0, stream>>>(sc, flag);

  // --- self attention ---
  k_layernorm<<<S, 256, 0, stream>>>(hidden, c_ln1g, c_ln1b, xln);
  k_gemm64<<<dim3(3072/128, S/64), 256, 0, stream>>>(xln, wT_cattn, c_catb,
      qkv, nullptr, S, 3072, 1024, 4, flag, 2048, vt_self);
  k_flash2<0,0><<<dim3(32, NHEAD, 4), 256, 0, stream>>>(
      qkv, 3*H, qkv + 1024, 3*H, vt_self, nullptr, obuf, mlbuf, 80);
  k_comb<0><<<dim3(S/16, NHEAD), 256, 0, stream>>>(obuf, mlbuf, attnout, 80);
  k_gemm64<<<dim3(1024/128, S/64), 256, 0, stream>>>(attnout, wT_aproj, c_aprb,
      nullptr, hidden, S, 1024, 1024, 2, flag, 0, nullptr);

  // --- cross attention ---
  k_layernorm<<<S, 256, 0, stream>>>(hidden, c_lnxg, c_lnxb, xln);
  k_gemm64<<<dim3(1024/128, S/64), 256, 0, stream>>>(xln, wT_qattn, c_qatb,
      q2, nullptr, S, 1024, 1024, 0, flag, 0, nullptr);
  k_gemm64<<<dim3(2048/128, SEQE/64), 256, 0, stream>>>(enc_c, wT_xkv, c_xkvb,
      kvbuf, nullptr, SEQE, 2048, 1024, 4, flag, 1024, vt_cross);
  k_flash2<2,1><<<dim3(32, NHEAD, 4), 256, 0, stream>>>(
      q2, H, kvbuf, 2*H, vt_cross, c_scor, obuf, mlbuf, 83);
  k_comb<2><<<dim3(S/16, NHEAD), 256, 0, stream>>>(obuf, mlbuf, attnout, 83);
  k_gemm64<<<dim3(1024/128, S/64), 256, 0, stream>>>(attnout, wT_xproj, c_xprb,
      nullptr, hidden, S, 1024, 1024, 2, flag, 0, nullptr);

  // --- MLP ---
  k_layernorm<<<S, 256, 0, stream>>>(hidden, c_ln2g, c_ln2b, xln);
  k_gemm64<<<dim3(INNER/128, S/64), 256, 0, stream>>>(xln, wT_fc, c_fcb,
      fcbuf, nullptr, S, INNER, 1024, 1, flag, 0, nullptr);
  k_gemm64<<<dim3(1024/128, S/64), 256, 0, stream>>>(fcbuf, wT_mlp, c_mlpb,
      out, hidden, S, 1024, INNER, 3, flag, 0, nullptr);
}

// Round 6
// 517.530 us; speedup vs baseline: 2.5177x; 1.0566x over previous
//
#include <hip/hip_runtime.h>
#include <stdint.h>

#define H     1024
#define S     2048
#define SEQE  2048
#define NHEAD 16
#define HD    64
#define INNER 4096
#define EPSLN 1e-5f
#define LOG2E 1.44269504089f
#define SCALE2 (0.125f * LOG2E)

typedef __attribute__((ext_vector_type(8))) short short8;
typedef __attribute__((ext_vector_type(4))) float floatx4;

__device__ __forceinline__ float b2f(unsigned short u){
  union { unsigned int i; float f; } v; v.i = ((unsigned int)u) << 16; return v.f;
}
__device__ __forceinline__ unsigned short f2b(float f){
  union { float f; unsigned int i; } v; v.f = f;
  unsigned int x = v.i;
  unsigned int r = (x + 0x7FFFu + ((x >> 16) & 1u)) >> 16;
  return (unsigned short)r;
}
__device__ __forceinline__ float gelu_tanh(float x){
  float x3 = x*x*x;
  float t = tanhf(0.7978845608028654f*(x + 0.044715f*x3));
  return 0.5f*x*(1.0f+t);
}

// async global->LDS, 16B per lane; LDS dest = wave-uniform base + lane*16
__device__ __forceinline__ void gld16(const unsigned short* g, unsigned short* l){
  __builtin_amdgcn_global_load_lds(
      (const __attribute__((address_space(1))) unsigned int*)g,
      (__attribute__((address_space(3))) unsigned int*)l,
      16, 0, 0);
}

// ---------------- dtype sniff ----------------
__global__ __launch_bounds__(256) void k_sniff(
    const unsigned short* __restrict__ p, int* __restrict__ flag){
  __shared__ int any;
  if (threadIdx.x == 0) any = 0;
  __syncthreads();
  int bad = 0;
  for (int i = threadIdx.x; i < 8192; i += 256){
    float v = b2f(p[i]);
    if (!(fabsf(v) < 1e6f)) bad = 1;
  }
  if (bad) any = 1;
  __syncthreads();
  if (threadIdx.x == 0) flag[0] = any;
}

// ---------------- flag-aware convert -> bf16 ----------------
__global__ __launch_bounds__(256) void k_cvt(
    const void* __restrict__ src, unsigned short* __restrict__ dst, int n,
    const int* __restrict__ flag){
  int i = blockIdx.x * 256 + threadIdx.x;
  if (i < n)
    dst[i] = flag[0] ? f2b(((const float*)src)[i]) : ((const unsigned short*)src)[i];
}

struct SmallCvt {
  const void* src[16];
  unsigned short* dst[16];
  int n[16];
};
__global__ __launch_bounds__(256) void k_cvt_small(SmallCvt sc, const int* __restrict__ flag){
  int t = blockIdx.x;
  int fl = flag[0];
  const float* sf = (const float*)sc.src[t];
  const unsigned short* sb = (const unsigned short*)sc.src[t];
  unsigned short* d = sc.dst[t];
  for (int i = threadIdx.x; i < sc.n[t]; i += 256)
    d[i] = fl ? f2b(sf[i]) : sb[i];
}

// ---------------- transpose W[R][C] -> WT[C][R] ----------------
__global__ __launch_bounds__(256) void k_transpose(
    const void* __restrict__ srcv, unsigned short* __restrict__ dst,
    int R, int C, const int* __restrict__ flag){
  __shared__ unsigned short t[32][33];
  const float* sf = (const float*)srcv;
  const unsigned short* sb = (const unsigned short*)srcv;
  int fl = flag[0];
  int bc = blockIdx.x * 32, br = blockIdx.y * 32;
  int tx = threadIdx.x, ty = threadIdx.y;
  #pragma unroll
  for (int i = 0; i < 4; i++){
    size_t idx = (size_t)(br + ty + i*8) * C + bc + tx;
    t[ty + i*8][tx] = fl ? f2b(sf[idx]) : sb[idx];
  }
  __syncthreads();
  #pragma unroll
  for (int i = 0; i < 4; i++)
    dst[(size_t)(bc + ty + i*8) * R + br + tx] = t[tx][ty + i*8];
}

// ---------------- residual init ----------------
__global__ __launch_bounds__(256) void k_resid_init(
    const void* __restrict__ in, float* __restrict__ out, int n,
    const int* __restrict__ flag){
  int i = blockIdx.x * 256 + threadIdx.x;
  if (i < n)
    out[i] = flag[0] ? ((const float*)in)[i] : b2f(((const unsigned short*)in)[i]);
}

// ---------------- LayerNorm ----------------
__global__ __launch_bounds__(256) void k_layernorm(
    const float* __restrict__ x,
    const unsigned short* __restrict__ g, const unsigned short* __restrict__ bb,
    unsigned short* __restrict__ y){
  __shared__ float scratch[4];
  int row = blockIdx.x, tid = threadIdx.x;
  float v[4];
  #pragma unroll
  for (int i=0;i<4;i++) v[i] = x[(size_t)row*H + tid + i*256];
  float s = v[0]+v[1]+v[2]+v[3];
  for (int o=32;o;o>>=1) s += __shfl_xor(s,o,64);
  int wid = tid>>6, lane = tid&63;
  if (lane==0) scratch[wid]=s;
  __syncthreads();
  float mu = (scratch[0]+scratch[1]+scratch[2]+scratch[3]) * (1.0f/H);
  __syncthreads();
  float q = 0.f;
  #pragma unroll
  for (int i=0;i<4;i++){ float d=v[i]-mu; q += d*d; }
  for (int o=32;o;o>>=1) q += __shfl_xor(q,o,64);
  if (lane==0) scratch[wid]=q;
  __syncthreads();
  float var = (scratch[0]+scratch[1]+scratch[2]+scratch[3]) * (1.0f/H);
  float rstd = rsqrtf(var + EPSLN);
  #pragma unroll
  for (int i=0;i<4;i++){
    int idx = tid + i*256;
    float o = (v[i]-mu)*rstd*b2f(g[idx]) + b2f(bb[idx]);
    y[(size_t)row*H + idx] = f2b(o);
  }
}

// ---------------- bf16 MFMA GEMM, 64x128 tile, BK=64, double-buffered async staging ----
// Pipeline per iter: barrier (drains tile-i loads, overlapped by iter i-1 compute)
//                    -> issue tile-(i+1) loads into other buffer -> compute tile i.
__global__ __launch_bounds__(256) void k_gemm64(
    const unsigned short* __restrict__ A, const unsigned short* __restrict__ BT,
    const unsigned short* __restrict__ bias,
    unsigned short* __restrict__ outb, float* __restrict__ resid,
    int M, int N, int K, int mode, const int* __restrict__ flag,
    int vcol0, unsigned short* __restrict__ vtout)
{
  __shared__ __align__(16) unsigned short As[2][64*64];    // 2 x 8 KB
  __shared__ __align__(16) unsigned short Bs[2][128*64];   // 2 x 16 KB
  int tid = threadIdx.x;
  int bm0 = blockIdx.y * 64, bn0 = blockIdx.x * 128;
  int wid = tid >> 6, lane = tid & 63;
  int wm = (wid & 1) * 32, wn = (wid >> 1) * 64;
  int fl = (mode == 3) ? flag[0] : 0;
  floatx4 acc[2][4] = {};

  // staging: 24 segments of 8 rows x 64 cols (1 KB each); wave w -> segs [6w, 6w+6)
  const unsigned short* gp[6];
  int lofs[6];   // element offset within As/Bs buffer
  int aseg[6];   // 1 if A, 0 if B
  int lrow = lane >> 3, lchunk = (lane & 7) ^ lrow;
  #pragma unroll
  for (int t = 0; t < 6; t++){
    int seg = wid * 6 + t;
    if (seg < 8){
      gp[t] = A + (size_t)(bm0 + seg*8 + lrow) * K + lchunk*8;
      lofs[t] = seg * 512;
      aseg[t] = 1;
    } else {
      int s = seg - 8;
      gp[t] = BT + (size_t)(bn0 + s*8 + lrow) * K + lchunk*8;
      lofs[t] = s * 512;
      aseg[t] = 0;
    }
  }

  // prologue: stage tile 0 into buffer 0
  #pragma unroll
  for (int t = 0; t < 6; t++)
    gld16(gp[t], (aseg[t] ? As[0] : Bs[0]) + lofs[t]);

  int mrow = lane & 15, quad = lane >> 4;
  int ib = 0;
  for (int kt = 0; kt < K; kt += 64, ib ^= 1){
    __syncthreads();   // drains tile-i loads (latency overlapped by prior compute)
    if (kt + 64 < K){
      #pragma unroll
      for (int t = 0; t < 6; t++)
        gld16(gp[t] + kt + 64, (aseg[t] ? As[ib^1] : Bs[ib^1]) + lofs[t]);
    }
    const unsigned short* Ac = As[ib];
    const unsigned short* Bc = Bs[ib];
    #pragma unroll
    for (int k2 = 0; k2 < 2; k2++){
      short8 af[2], bf[4];
      #pragma unroll
      for (int i = 0; i < 2; i++){
        int r = wm + i*16 + mrow;
        int slot = (k2*4 + quad) ^ (r & 7);
        af[i] = *(const short8*)&Ac[r*64 + slot*8];
      }
      #pragma unroll
      for (int j = 0; j < 4; j++){
        int r = wn + j*16 + mrow;
        int slot = (k2*4 + quad) ^ (r & 7);
        bf[j] = *(const short8*)&Bc[r*64 + slot*8];
      }
      #pragma unroll
      for (int i = 0; i < 2; i++){
        #pragma unroll
        for (int j = 0; j < 4; j++){
          acc[i][j] = __builtin_amdgcn_mfma_f32_16x16x32_bf16(af[i], bf[j], acc[i][j], 0,0,0);
        }
      }
    }
  }

  int colb = mrow, rowb = quad * 4;
  #pragma unroll
  for (int i=0;i<2;i++){
    #pragma unroll
    for (int j=0;j<4;j++){
      int col = bn0 + wn + j*16 + colb;
      float bv = b2f(bias[col]);
      int row0 = bm0 + wm + i*16 + rowb;
      if (mode == 4 && col >= vcol0){
        ushort4 uv;
        uv.x = f2b(acc[i][j][0] + bv);
        uv.y = f2b(acc[i][j][1] + bv);
        uv.z = f2b(acc[i][j][2] + bv);
        uv.w = f2b(acc[i][j][3] + bv);
        *(ushort4*)(vtout + (size_t)(col - vcol0)*M + row0) = uv;
      } else {
        #pragma unroll
        for (int rr=0;rr<4;rr++){
          int row = row0 + rr;
          float v = acc[i][j][rr] + bv;
          size_t off = (size_t)row*N + col;
          if      (mode == 0 || mode == 4){ outb[off] = f2b(v); }
          else if (mode == 1){ outb[off] = f2b(gelu_tanh(v)); }
          else if (mode == 2){ resid[off] += v; }
          else {
            float o = v + resid[off];
            if (fl) ((float*)outb)[off] = o;
            else    outb[off] = f2b(o);
          }
        }
      }
    }
  }
}

// ---------------- split-K flash attention (MFMA, exp2 domain, partials) ----------------
template<int CA, int SCOR>
__global__ __launch_bounds__(256) void k_flash2(
    const unsigned short* __restrict__ qb, int qstride,
    const unsigned short* __restrict__ kb, int kstride,
    const unsigned short* __restrict__ vt,
    const unsigned short* __restrict__ scorer,
    unsigned short* __restrict__ obuf, float* __restrict__ mlbuf, int TOTS)
{
  int t = blockIdx.x, h = blockIdx.y, sp = blockIdx.z;
  int klmax0 = 64*t + 64 + CA; if (klmax0 > S) klmax0 = S;
  int nch = (klmax0 + 63) >> 6;
  int nsp = (nch + 7) >> 3;
  if (sp >= nsp) return;
  int base = 0;
  for (int i = 0; i < t; i++){
    int km = 64*i + 64 + CA; if (km > S) km = S;
    base += (((km + 63) >> 6) + 7) >> 3;
  }
  int pidx = h*TOTS + base + sp;
  int c0 = sp*8, c1 = c0 + 8; if (c1 > nch) c1 = nch;

  __shared__ __align__(16) unsigned short Ks[64*64];
  __shared__ __align__(16) unsigned short VTs[64*64];
  __shared__ __align__(16) unsigned short Ps[4][16*72];
  __shared__ float scs[64];
  int tid = threadIdx.x;
  int q0 = t*64;
  int w = tid >> 6, lane = tid & 63;
  int cn = lane & 15, quad = lane >> 4, kq = quad * 8;
  unsigned short* Pw = Ps[w];
  int srow0 = w*16;
  int lr = lane >> 3;
  int lc = ((lane & 7) ^ lr) * 8;
  const unsigned short* kg0 = kb + (size_t)(srow0 + lr) * kstride + h*HD + lc;
  const unsigned short* kg1 = kb + (size_t)(srow0 + 8 + lr) * kstride + h*HD + lc;
  const unsigned short* vg0 = vt + (size_t)(h*HD + srow0 + lr) * S + lc;
  const unsigned short* vg1 = vt + (size_t)(h*HD + srow0 + 8 + lr) * S + lc;
  unsigned short* kl0 = &Ks[srow0 * 64];
  unsigned short* kl1 = &Ks[(srow0 + 8) * 64];
  unsigned short* vl0 = &VTs[srow0 * 64];
  unsigned short* vl1 = &VTs[(srow0 + 8) * 64];

  const unsigned short* qrow = qb + (size_t)(q0 + w*16 + cn) * qstride + h*HD;
  short8 qf0 = *(const short8*)(qrow + kq);
  short8 qf1 = *(const short8*)(qrow + kq + 32);
  floatx4 oacc[4] = {};
  float l_lane[4] = {0,0,0,0};
  float m_w = -1.0e38f;
  int qmr = q0 + w*16 + quad*4;

  for (int ci = c0; ci < c1; ci++){
    int kc = ci * 64;
    __syncthreads();
    gld16(kg0 + (size_t)kc * kstride, kl0);
    gld16(kg1 + (size_t)kc * kstride, kl1);
    gld16(vg0 + kc, vl0);
    gld16(vg1 + kc, vl1);
    if (SCOR && tid < 64) scs[tid] = b2f(scorer[kc + tid]) * LOG2E;
    __syncthreads();

    floatx4 sv[4] = {};
    #pragma unroll
    for (int t4=0;t4<4;t4++){
      int rr = t4*16 + cn;
      int s0 = ((quad    ) ^ (rr & 7)) * 8;
      int s1 = ((quad + 4) ^ (rr & 7)) * 8;
      short8 b0 = *(const short8*)&Ks[rr*64 + s0];
      short8 b1 = *(const short8*)&Ks[rr*64 + s1];
      sv[t4] = __builtin_amdgcn_mfma_f32_16x16x32_bf16(qf0, b0, sv[t4], 0,0,0);
      sv[t4] = __builtin_amdgcn_mfma_f32_16x16x32_bf16(qf1, b1, sv[t4], 0,0,0);
    }

    float vals[16];
    float lmax = -1.0e38f;
    bool needmask = (kc + 63 > q0 + w*16 + CA);
    #pragma unroll
    for (int t4=0;t4<4;t4++){
      #pragma unroll
      for (int r=0;r<4;r++){
        float s = sv[t4][r] * SCALE2;
        if (SCOR) s += scs[t4*16 + cn];
        if (needmask){
          int kn = kc + t4*16 + cn;
          s = (kn <= qmr + r + CA) ? s : -1.0e38f;
        }
        vals[t4*4+r] = s;
        lmax = fmaxf(lmax, s);
      }
    }
    #pragma unroll
    for (int o=1;o<64;o<<=1) lmax = fmaxf(lmax, __shfl_xor(lmax, o, 64));
    if (lmax > m_w){
      float al = exp2f(m_w - lmax);
      m_w = lmax;
      #pragma unroll
      for (int r=0;r<4;r++) l_lane[r] *= al;
      #pragma unroll
      for (int t2=0;t2<4;t2++){
        #pragma unroll
        for (int r=0;r<4;r++) oacc[t2][r] *= al;
      }
    }
    #pragma unroll
    for (int t4=0;t4<4;t4++){
      #pragma unroll
      for (int r=0;r<4;r++){
        float e = exp2f(vals[t4*4+r] - m_w);
        l_lane[r] += e;
        Pw[(quad*4+r)*72 + t4*16 + cn] = f2b(e);
      }
    }
    short8 pf0 = *(const short8*)&Pw[cn*72 + kq];
    short8 pf1 = *(const short8*)&Pw[cn*72 + kq + 32];
    #pragma unroll
    for (int t2=0;t2<4;t2++){
      int rr = t2*16 + cn;
      int s0 = ((quad    ) ^ (rr & 7)) * 8;
      int s1 = ((quad + 4) ^ (rr & 7)) * 8;
      short8 v0 = *(const short8*)&VTs[rr*64 + s0];
      short8 v1 = *(const short8*)&VTs[rr*64 + s1];
      oacc[t2] = __builtin_amdgcn_mfma_f32_16x16x32_bf16(pf0, v0, oacc[t2], 0,0,0);
      oacc[t2] = __builtin_amdgcn_mfma_f32_16x16x32_bf16(pf1, v1, oacc[t2], 0,0,0);
    }
  }

  float lrow[4];
  #pragma unroll
  for (int r=0;r<4;r++){
    float l = l_lane[r];
    l += __shfl_xor(l,1,64); l += __shfl_xor(l,2,64);
    l += __shfl_xor(l,4,64); l += __shfl_xor(l,8,64);
    lrow[r] = l;
  }
  size_t ob = (size_t)pidx*4096 + (size_t)(w*16 + quad*4)*64;
  #pragma unroll
  for (int t2=0;t2<4;t2++){
    #pragma unroll
    for (int r=0;r<4;r++)
      obuf[ob + r*64 + t2*16 + cn] = f2b(oacc[t2][r]);
  }
  if (cn == 0){
    #pragma unroll
    for (int r=0;r<4;r++){
      int row64 = w*16 + quad*4 + r;
      mlbuf[((size_t)pidx*64 + row64)*2]   = m_w;
      mlbuf[((size_t)pidx*64 + row64)*2+1] = lrow[r];
    }
  }
}

// ---------------- split-K combine ----------------
template<int CA>
__global__ __launch_bounds__(256) void k_comb(
    const unsigned short* __restrict__ obuf, const float* __restrict__ mlbuf,
    unsigned short* __restrict__ out, int TOTS)
{
  int h = blockIdx.y;
  int row = blockIdx.x*16 + (threadIdx.x >> 4);
  int d0 = (threadIdx.x & 15) * 4;
  int t = row >> 6;
  int klmax0 = 64*t + 64 + CA; if (klmax0 > S) klmax0 = S;
  int nch = (klmax0 + 63) >> 6;
  int nsp = (nch + 7) >> 3;
  int base = 0;
  for (int i = 0; i < t; i++){
    int km = 64*i + 64 + CA; if (km > S) km = S;
    base += (((km + 63) >> 6) + 7) >> 3;
  }
  int row64 = row & 63;
  float mp[4], lp[4];
  float M = -1.0e38f;
  for (int p = 0; p < nsp; p++){
    int pi = h*TOTS + base + p;
    mp[p] = mlbuf[((size_t)pi*64 + row64)*2];
    lp[p] = mlbuf[((size_t)pi*64 + row64)*2+1];
    M = fmaxf(M, mp[p]);
  }
  float L = 0.f;
  float o0=0.f,o1=0.f,o2=0.f,o3=0.f;
  for (int p = 0; p < nsp; p++){
    int pi = h*TOTS + base + p;
    float wgt = exp2f(mp[p] - M);
    L += lp[p]*wgt;
    const unsigned short* op = obuf + (size_t)pi*4096 + row64*64 + d0;
    o0 += b2f(op[0])*wgt; o1 += b2f(op[1])*wgt;
    o2 += b2f(op[2])*wgt; o3 += b2f(op[3])*wgt;
  }
  float inv = 1.0f / L;
  size_t oo = (size_t)row*H + h*HD + d0;
  out[oo]   = f2b(o0*inv); out[oo+1] = f2b(o1*inv);
  out[oo+2] = f2b(o2*inv); out[oo+3] = f2b(o3*inv);
}

extern "C" void kernel_launch(void* const* d_in, const int* in_sizes, int n_in,
                              void* d_out, int out_size, void* d_ws, size_t ws_size,
                              hipStream_t stream)
{
  const void* hs          = d_in[0];
  const void* enc         = d_in[1];
  const void* scorer      = d_in[2];
  const void* ln1_g       = d_in[3];
  const void* ln1_b       = d_in[4];
  const void* c_attn_w    = d_in[5];
  const void* c_attn_b    = d_in[6];
  const void* attn_proj_w = d_in[7];
  const void* attn_proj_b = d_in[8];
  const void* lnx_g       = d_in[9];
  const void* lnx_b       = d_in[10];
  const void* q_attn_w    = d_in[11];
  const void* q_attn_b    = d_in[12];
  const void* x_kv_w      = d_in[13];
  const void* x_kv_b      = d_in[14];
  const void* x_proj_w    = d_in[15];
  const void* x_proj_b    = d_in[16];
  const void* ln2_g       = d_in[17];
  const void* ln2_b       = d_in[18];
  const void* fc_w        = d_in[19];
  const void* fc_b        = d_in[20];
  const void* mlp_proj_w  = d_in[21];
  const void* mlp_proj_b  = d_in[22];
  unsigned short* out = (unsigned short*)d_out;

  char* ws = (char*)d_ws; size_t off = 0;
  auto alloc = [&](size_t bytes)->void*{
    void* p = ws + off; off += (bytes + 255) & ~(size_t)255; return p;
  };
  unsigned short* wT_cattn = (unsigned short*)alloc((size_t)3072*1024*2);
  unsigned short* wT_aproj = (unsigned short*)alloc((size_t)1024*1024*2);
  unsigned short* wT_qattn = (unsigned short*)alloc((size_t)1024*1024*2);
  unsigned short* wT_xkv   = (unsigned short*)alloc((size_t)2048*1024*2);
  unsigned short* wT_xproj = (unsigned short*)alloc((size_t)1024*1024*2);
  unsigned short* wT_fc    = (unsigned short*)alloc((size_t)4096*1024*2);
  unsigned short* wT_mlp   = (unsigned short*)alloc((size_t)1024*4096*2);
  unsigned short* enc_c    = (unsigned short*)alloc((size_t)SEQE*H*2);
  unsigned short* canon    = (unsigned short*)alloc((size_t)32768*2);
  unsigned short* xln      = (unsigned short*)alloc((size_t)S*H*2);
  unsigned short* qkv      = (unsigned short*)alloc((size_t)S*3*H*2);
  unsigned short* attnout  = (unsigned short*)alloc((size_t)S*H*2);
  unsigned short* q2       = (unsigned short*)alloc((size_t)S*H*2);
  unsigned short* kvbuf    = (unsigned short*)alloc((size_t)SEQE*2*H*2);
  unsigned short* vt_self  = (unsigned short*)alloc((size_t)H*S*2);
  unsigned short* vt_cross = (unsigned short*)alloc((size_t)H*SEQE*2);
  unsigned short* fcbuf    = (unsigned short*)alloc((size_t)S*INNER*2);
  float*          hidden   = (float*)alloc((size_t)S*H*4);
  int*            flag     = (int*)alloc(256);

  // flash partials aliased into fcbuf (fcbuf only used in MLP phase)
  unsigned short* obuf  = fcbuf;
  float*          mlbuf = (float*)(fcbuf + (size_t)16*83*4096);

  unsigned short* p = canon;
  auto carve = [&](int n)->unsigned short*{ unsigned short* q = p; p += n; return q; };
  unsigned short* c_ln1g = carve(1024); unsigned short* c_ln1b = carve(1024);
  unsigned short* c_catb = carve(3072); unsigned short* c_aprb = carve(1024);
  unsigned short* c_lnxg = carve(1024); unsigned short* c_lnxb = carve(1024);
  unsigned short* c_qatb = carve(1024); unsigned short* c_xkvb = carve(2048);
  unsigned short* c_xprb = carve(1024); unsigned short* c_ln2g = carve(1024);
  unsigned short* c_ln2b = carve(1024); unsigned short* c_fcb  = carve(4096);
  unsigned short* c_mlpb = carve(1024); unsigned short* c_scor = carve(2048);

  k_sniff<<<1, 256, 0, stream>>>((const unsigned short*)hs, flag);
  k_resid_init<<<(S*H)/256, 256, 0, stream>>>(hs, hidden, S*H, flag);

  dim3 tb(32,8);
  k_transpose<<<dim3(3072/32,1024/32), tb, 0, stream>>>(c_attn_w,    wT_cattn, 1024, 3072, flag);
  k_transpose<<<dim3(1024/32,1024/32), tb, 0, stream>>>(attn_proj_w, wT_aproj, 1024, 1024, flag);
  k_transpose<<<dim3(1024/32,1024/32), tb, 0, stream>>>(q_attn_w,    wT_qattn, 1024, 1024, flag);
  k_transpose<<<dim3(2048/32,1024/32), tb, 0, stream>>>(x_kv_w,      wT_xkv,   1024, 2048, flag);
  k_transpose<<<dim3(1024/32,1024/32), tb, 0, stream>>>(x_proj_w,    wT_xproj, 1024, 1024, flag);
  k_transpose<<<dim3(4096/32,1024/32), tb, 0, stream>>>(fc_w,        wT_fc,    1024, 4096, flag);
  k_transpose<<<dim3(1024/32,4096/32), tb, 0, stream>>>(mlp_proj_w,  wT_mlp,   4096, 1024, flag);

  k_cvt<<<(SEQE*H)/256, 256, 0, stream>>>(enc, enc_c, SEQE*H, flag);
  SmallCvt sc{};
  const void* ssrc[14] = {ln1_g, ln1_b, c_attn_b, attn_proj_b, lnx_g, lnx_b,
                          q_attn_b, x_kv_b, x_proj_b, ln2_g, ln2_b, fc_b,
                          mlp_proj_b, scorer};
  unsigned short* sdst[14] = {c_ln1g, c_ln1b, c_catb, c_aprb, c_lnxg, c_lnxb,
                              c_qatb, c_xkvb, c_xprb, c_ln2g, c_ln2b, c_fcb,
                              c_mlpb, c_scor};
  int sn[14] = {1024,1024,3072,1024,1024,1024,1024,2048,1024,1024,1024,4096,1024,2048};
  for (int i=0;i<14;i++){ sc.src[i]=ssrc[i]; sc.dst[i]=sdst[i]; sc.n[i]=sn[i]; }
  k_cvt_small<<<14, 256, 0, stream>>>(sc, flag);

  // --- self attention ---
  k_layernorm<<<S, 256, 0, stream>>>(hidden, c_ln1g, c_ln1b, xln);
  k_gemm64<<<dim3(3072/128, S/64), 256, 0, stream>>>(xln, wT_cattn, c_catb,
      qkv, nullptr, S, 3072, 1024, 4, flag, 2048, vt_self);
  k_flash2<0,0><<<dim3(32, NHEAD, 4), 256, 0, stream>>>(
      qkv, 3*H, qkv + 1024, 3*H, vt_self, nullptr, obuf, mlbuf, 80);
  k_comb<0><<<dim3(S/16, NHEAD), 256, 0, stream>>>(obuf, mlbuf, attnout, 80);
  k_gemm64<<<dim3(1024/128, S/64), 256, 0, stream>>>(attnout, wT_aproj, c_aprb,
      nullptr, hidden, S, 1024, 1024, 2, flag, 0, nullptr);

  // --- cross attention ---
  k_layernorm<<<S, 256, 0, stream>>>(hidden, c_lnxg, c_lnxb, xln);
  k_gemm64<<<dim3(1024/128, S/64), 256, 0, stream>>>(xln, wT_qattn, c_qatb,
      q2, nullptr, S, 1024, 1024, 0, flag, 0, nullptr);
  k_gemm64<<<dim3(2048/128, SEQE/64), 256, 0, stream>>>(enc_c, wT_xkv, c_xkvb,
      kvbuf, nullptr, SEQE, 2048, 1024, 4, flag, 1024, vt_cross);
  k_flash2<2,1><<<dim3(32, NHEAD, 4), 256, 0, stream>>>(
      q2, H, kvbuf, 2*H, vt_cross, c_scor, obuf, mlbuf, 83);
  k_comb<2><<<dim3(S/16, NHEAD), 256, 0, stream>>>(obuf, mlbuf, attnout, 83);
  k_gemm64<<<dim3(1024/128, S/64), 256, 0, stream>>>(attnout, wT_xproj, c_xprb,
      nullptr, hidden, S, 1024, 1024, 2, flag, 0, nullptr);

  // --- MLP ---
  k_layernorm<<<S, 256, 0, stream>>>(hidden, c_ln2g, c_ln2b, xln);
  k_gemm64<<<dim3(INNER/128, S/64), 256, 0, stream>>>(xln, wT_fc, c_fcb,
      fcbuf, nullptr, S, INNER, 1024, 1, flag, 0, nullptr);
  k_gemm64<<<dim3(1024/128, S/64), 256, 0, stream>>>(fcbuf, wT_mlp, c_mlpb,
      out, hidden, S, 1024, INNER, 3, flag, 0, nullptr);
}

// Round 7
// 511.047 us; speedup vs baseline: 2.5496x; 1.0127x over previous
//
#include <hip/hip_runtime.h>
#include <stdint.h>

#define H     1024
#define S     2048
#define SEQE  2048
#define NHEAD 16
#define HD    64
#define INNER 4096
#define EPSLN 1e-5f
#define LOG2E 1.44269504089f
#define SCALE2 (0.125f * LOG2E)

typedef __attribute__((ext_vector_type(8))) short short8;
typedef __attribute__((ext_vector_type(4))) float floatx4;

__device__ __forceinline__ float b2f(unsigned short u){
  union { unsigned int i; float f; } v; v.i = ((unsigned int)u) << 16; return v.f;
}
__device__ __forceinline__ unsigned short f2b(float f){
  union { float f; unsigned int i; } v; v.f = f;
  unsigned int x = v.i;
  unsigned int r = (x + 0x7FFFu + ((x >> 16) & 1u)) >> 16;
  return (unsigned short)r;
}
__device__ __forceinline__ float gelu_tanh(float x){
  float x3 = x*x*x;
  float t = tanhf(0.7978845608028654f*(x + 0.044715f*x3));
  return 0.5f*x*(1.0f+t);
}

// async global->LDS, 16B per lane; LDS dest = wave-uniform base + lane*16
__device__ __forceinline__ void gld16(const unsigned short* g, unsigned short* l){
  __builtin_amdgcn_global_load_lds(
      (const __attribute__((address_space(1))) unsigned int*)g,
      (__attribute__((address_space(3))) unsigned int*)l,
      16, 0, 0);
}

// ---------------- dtype sniff ----------------
__global__ __launch_bounds__(256) void k_sniff(
    const unsigned short* __restrict__ p, int* __restrict__ flag){
  __shared__ int any;
  if (threadIdx.x == 0) any = 0;
  __syncthreads();
  int bad = 0;
  for (int i = threadIdx.x; i < 8192; i += 256){
    float v = b2f(p[i]);
    if (!(fabsf(v) < 1e6f)) bad = 1;
  }
  if (bad) any = 1;
  __syncthreads();
  if (threadIdx.x == 0) flag[0] = any;
}

// ---------------- fused weight transposes: src[R][C] -> dst[C][R], 7 matrices ----------
struct PrepT {
  const void* src[7];
  unsigned short* dst[7];
  int R[7], C[7];
  int pre[8];
};
__global__ __launch_bounds__(256) void k_prep_t(PrepT d, const int* __restrict__ flag){
  __shared__ unsigned short t[32][33];
  int b = blockIdx.x;
  int m = 0;
  while (b >= d.pre[m+1]) m++;
  int ti = b - d.pre[m];
  int R = d.R[m], C = d.C[m];
  int tx = threadIdx.x & 31, ty = threadIdx.x >> 5;
  int tilesx = C >> 5;
  int bc = (ti % tilesx) << 5, br = (ti / tilesx) << 5;
  const float* sf = (const float*)d.src[m];
  const unsigned short* sb = (const unsigned short*)d.src[m];
  unsigned short* dst = d.dst[m];
  int fl = flag[0];
  #pragma unroll
  for (int i = 0; i < 4; i++){
    size_t idx = (size_t)(br + ty + i*8) * C + bc + tx;
    t[ty + i*8][tx] = fl ? f2b(sf[idx]) : sb[idx];
  }
  __syncthreads();
  #pragma unroll
  for (int i = 0; i < 4; i++)
    dst[(size_t)(bc + ty + i*8) * R + br + tx] = t[tx][ty + i*8];
}

// ---------------- fused converts: enc->bf16, hs->fp32 resid, 14 small tensors ---------
struct SmallCvt {
  const void* src[16];
  unsigned short* dst[16];
  int n[16];
};
__global__ __launch_bounds__(256) void k_prep_c(
    const void* __restrict__ enc, unsigned short* __restrict__ enc_c,
    const void* __restrict__ hsv, float* __restrict__ hidden,
    SmallCvt sc, const int* __restrict__ flag){
  int b = blockIdx.x, tid = threadIdx.x;
  int fl = flag[0];
  if (b < 8192){
    int i = b*256 + tid;
    enc_c[i] = fl ? f2b(((const float*)enc)[i]) : ((const unsigned short*)enc)[i];
  } else if (b < 16384){
    int i = (b - 8192)*256 + tid;
    hidden[i] = fl ? ((const float*)hsv)[i] : b2f(((const unsigned short*)hsv)[i]);
  } else {
    int t = b - 16384;
    const float* sf = (const float*)sc.src[t];
    const unsigned short* sb = (const unsigned short*)sc.src[t];
    unsigned short* d = sc.dst[t];
    for (int i = tid; i < sc.n[t]; i += 256)
      d[i] = fl ? f2b(sf[i]) : sb[i];
  }
}

// ---------------- LayerNorm ----------------
__global__ __launch_bounds__(256) void k_layernorm(
    const float* __restrict__ x,
    const unsigned short* __restrict__ g, const unsigned short* __restrict__ bb,
    unsigned short* __restrict__ y){
  __shared__ float scratch[4];
  int row = blockIdx.x, tid = threadIdx.x;
  float v[4];
  #pragma unroll
  for (int i=0;i<4;i++) v[i] = x[(size_t)row*H + tid + i*256];
  float s = v[0]+v[1]+v[2]+v[3];
  for (int o=32;o;o>>=1) s += __shfl_xor(s,o,64);
  int wid = tid>>6, lane = tid&63;
  if (lane==0) scratch[wid]=s;
  __syncthreads();
  float mu = (scratch[0]+scratch[1]+scratch[2]+scratch[3]) * (1.0f/H);
  __syncthreads();
  float q = 0.f;
  #pragma unroll
  for (int i=0;i<4;i++){ float d=v[i]-mu; q += d*d; }
  for (int o=32;o;o>>=1) q += __shfl_xor(q,o,64);
  if (lane==0) scratch[wid]=q;
  __syncthreads();
  float var = (scratch[0]+scratch[1]+scratch[2]+scratch[3]) * (1.0f/H);
  float rstd = rsqrtf(var + EPSLN);
  #pragma unroll
  for (int i=0;i<4;i++){
    int idx = tid + i*256;
    float o = (v[i]-mu)*rstd*b2f(g[idx]) + b2f(bb[idx]);
    y[(size_t)row*H + idx] = f2b(o);
  }
}

// ---------------- bf16 MFMA GEMM, 64x128 tile, BK=64, double-buffered async staging ----
__global__ __launch_bounds__(256) void k_gemm64(
    const unsigned short* __restrict__ A, const unsigned short* __restrict__ BT,
    const unsigned short* __restrict__ bias,
    unsigned short* __restrict__ outb, float* __restrict__ resid,
    int M, int N, int K, int mode, const int* __restrict__ flag,
    int vcol0, unsigned short* __restrict__ vtout)
{
  __shared__ __align__(16) unsigned short As[2][64*64];
  __shared__ __align__(16) unsigned short Bs[2][128*64];
  int tid = threadIdx.x;
  int bm0 = blockIdx.y * 64, bn0 = blockIdx.x * 128;
  int wid = tid >> 6, lane = tid & 63;
  int wm = (wid & 1) * 32, wn = (wid >> 1) * 64;
  int fl = (mode == 3) ? flag[0] : 0;
  floatx4 acc[2][4] = {};

  const unsigned short* gp[6];
  int lofs[6];
  int aseg[6];
  int lrow = lane >> 3, lchunk = (lane & 7) ^ lrow;
  #pragma unroll
  for (int t = 0; t < 6; t++){
    int seg = wid * 6 + t;
    if (seg < 8){
      gp[t] = A + (size_t)(bm0 + seg*8 + lrow) * K + lchunk*8;
      lofs[t] = seg * 512;
      aseg[t] = 1;
    } else {
      int s = seg - 8;
      gp[t] = BT + (size_t)(bn0 + s*8 + lrow) * K + lchunk*8;
      lofs[t] = s * 512;
      aseg[t] = 0;
    }
  }

  #pragma unroll
  for (int t = 0; t < 6; t++)
    gld16(gp[t], (aseg[t] ? As[0] : Bs[0]) + lofs[t]);

  int mrow = lane & 15, quad = lane >> 4;
  int ib = 0;
  for (int kt = 0; kt < K; kt += 64, ib ^= 1){
    __syncthreads();
    if (kt + 64 < K){
      #pragma unroll
      for (int t = 0; t < 6; t++)
        gld16(gp[t] + kt + 64, (aseg[t] ? As[ib^1] : Bs[ib^1]) + lofs[t]);
    }
    const unsigned short* Ac = As[ib];
    const unsigned short* Bc = Bs[ib];
    #pragma unroll
    for (int k2 = 0; k2 < 2; k2++){
      short8 af[2], bf[4];
      #pragma unroll
      for (int i = 0; i < 2; i++){
        int r = wm + i*16 + mrow;
        int slot = (k2*4 + quad) ^ (r & 7);
        af[i] = *(const short8*)&Ac[r*64 + slot*8];
      }
      #pragma unroll
      for (int j = 0; j < 4; j++){
        int r = wn + j*16 + mrow;
        int slot = (k2*4 + quad) ^ (r & 7);
        bf[j] = *(const short8*)&Bc[r*64 + slot*8];
      }
      #pragma unroll
      for (int i = 0; i < 2; i++){
        #pragma unroll
        for (int j = 0; j < 4; j++){
          acc[i][j] = __builtin_amdgcn_mfma_f32_16x16x32_bf16(af[i], bf[j], acc[i][j], 0,0,0);
        }
      }
    }
  }

  int colb = mrow, rowb = quad * 4;
  #pragma unroll
  for (int i=0;i<2;i++){
    #pragma unroll
    for (int j=0;j<4;j++){
      int col = bn0 + wn + j*16 + colb;
      float bv = b2f(bias[col]);
      int row0 = bm0 + wm + i*16 + rowb;
      if (mode == 4 && col >= vcol0){
        ushort4 uv;
        uv.x = f2b(acc[i][j][0] + bv);
        uv.y = f2b(acc[i][j][1] + bv);
        uv.z = f2b(acc[i][j][2] + bv);
        uv.w = f2b(acc[i][j][3] + bv);
        *(ushort4*)(vtout + (size_t)(col - vcol0)*M + row0) = uv;
      } else {
        #pragma unroll
        for (int rr=0;rr<4;rr++){
          int row = row0 + rr;
          float v = acc[i][j][rr] + bv;
          size_t off = (size_t)row*N + col;
          if      (mode == 0 || mode == 4){ outb[off] = f2b(v); }
          else if (mode == 1){ outb[off] = f2b(gelu_tanh(v)); }
          else if (mode == 2){ resid[off] += v; }
          else {
            float o = v + resid[off];
            if (fl) ((float*)outb)[off] = o;
            else    outb[off] = f2b(o);
          }
        }
      }
    }
  }
}

// ---------------- split-K flash attention (double-buffered staging) ----------------
template<int CA, int SCOR>
__global__ __launch_bounds__(256) void k_flash2(
    const unsigned short* __restrict__ qb, int qstride,
    const unsigned short* __restrict__ kb, int kstride,
    const unsigned short* __restrict__ vt,
    const unsigned short* __restrict__ scorer,
    unsigned short* __restrict__ obuf, float* __restrict__ mlbuf, int TOTS)
{
  int t = blockIdx.x, h = blockIdx.y, sp = blockIdx.z;
  int klmax0 = 64*t + 64 + CA; if (klmax0 > S) klmax0 = S;
  int nch = (klmax0 + 63) >> 6;
  int nsp = (nch + 7) >> 3;
  if (sp >= nsp) return;
  int base = 0;
  for (int i = 0; i < t; i++){
    int km = 64*i + 64 + CA; if (km > S) km = S;
    base += (((km + 63) >> 6) + 7) >> 3;
  }
  int pidx = h*TOTS + base + sp;
  int c0 = sp*8, c1 = c0 + 8; if (c1 > nch) c1 = nch;

  __shared__ __align__(16) unsigned short Ks[2][64*64];
  __shared__ __align__(16) unsigned short VTs[2][64*64];
  __shared__ __align__(16) unsigned short Ps[4][16*72];
  __shared__ float scs[2][64];
  int tid = threadIdx.x;
  int q0 = t*64;
  int w = tid >> 6, lane = tid & 63;
  int cn = lane & 15, quad = lane >> 4, kq = quad * 8;
  unsigned short* Pw = Ps[w];
  int srow0 = w*16;
  int lr = lane >> 3;
  int lc = ((lane & 7) ^ lr) * 8;
  const unsigned short* kg0 = kb + (size_t)(srow0 + lr) * kstride + h*HD + lc;
  const unsigned short* kg1 = kb + (size_t)(srow0 + 8 + lr) * kstride + h*HD + lc;
  const unsigned short* vg0 = vt + (size_t)(h*HD + srow0 + lr) * S + lc;
  const unsigned short* vg1 = vt + (size_t)(h*HD + srow0 + 8 + lr) * S + lc;

  const unsigned short* qrow = qb + (size_t)(q0 + w*16 + cn) * qstride + h*HD;
  short8 qf0 = *(const short8*)(qrow + kq);
  short8 qf1 = *(const short8*)(qrow + kq + 32);
  floatx4 oacc[4] = {};
  float l_lane[4] = {0,0,0,0};
  float m_w = -1.0e38f;
  int qmr = q0 + w*16 + quad*4;

  // prologue: stage chunk c0 into buffer 0
  {
    int kc = c0 * 64;
    gld16(kg0 + (size_t)kc * kstride, Ks[0] + srow0*64);
    gld16(kg1 + (size_t)kc * kstride, Ks[0] + (srow0 + 8)*64);
    gld16(vg0 + kc, VTs[0] + srow0*64);
    gld16(vg1 + kc, VTs[0] + (srow0 + 8)*64);
    if (SCOR && tid < 64) scs[0][tid] = b2f(scorer[kc + tid]) * LOG2E;
  }

  int ib = 0;
  for (int ci = c0; ci < c1; ci++, ib ^= 1){
    __syncthreads();   // drains chunk-ci loads (latency covered by chunk ci-1 compute)
    if (ci + 1 < c1){
      int kn2 = (ci + 1) * 64;
      gld16(kg0 + (size_t)kn2 * kstride, Ks[ib^1] + srow0*64);
      gld16(kg1 + (size_t)kn2 * kstride, Ks[ib^1] + (srow0 + 8)*64);
      gld16(vg0 + kn2, VTs[ib^1] + srow0*64);
      gld16(vg1 + kn2, VTs[ib^1] + (srow0 + 8)*64);
      if (SCOR && tid < 64) scs[ib^1][tid] = b2f(scorer[kn2 + tid]) * LOG2E;
    }
    int kc = ci * 64;
    const unsigned short* Kc = Ks[ib];
    const unsigned short* Vc = VTs[ib];
    const float* scc = scs[ib];

    floatx4 sv[4] = {};
    #pragma unroll
    for (int t4=0;t4<4;t4++){
      int rr = t4*16 + cn;
      int s0 = ((quad    ) ^ (rr & 7)) * 8;
      int s1 = ((quad + 4) ^ (rr & 7)) * 8;
      short8 b0 = *(const short8*)&Kc[rr*64 + s0];
      short8 b1 = *(const short8*)&Kc[rr*64 + s1];
      sv[t4] = __builtin_amdgcn_mfma_f32_16x16x32_bf16(qf0, b0, sv[t4], 0,0,0);
      sv[t4] = __builtin_amdgcn_mfma_f32_16x16x32_bf16(qf1, b1, sv[t4], 0,0,0);
    }

    float vals[16];
    float lmax = -1.0e38f;
    if (kc + 63 > q0 + w*16 + CA){          // wave-uniform: diagonal (masked) chunk
      #pragma unroll
      for (int t4=0;t4<4;t4++){
        #pragma unroll
        for (int r=0;r<4;r++){
          float s = sv[t4][r] * SCALE2;
          if (SCOR) s += scc[t4*16 + cn];
          int kn = kc + t4*16 + cn;
          s = (kn <= qmr + r + CA) ? s : -1.0e38f;
          vals[t4*4+r] = s;
          lmax = fmaxf(lmax, s);
        }
      }
    } else {
      #pragma unroll
      for (int t4=0;t4<4;t4++){
        #pragma unroll
        for (int r=0;r<4;r++){
          float s = sv[t4][r] * SCALE2;
          if (SCOR) s += scc[t4*16 + cn];
          vals[t4*4+r] = s;
          lmax = fmaxf(lmax, s);
        }
      }
    }
    #pragma unroll
    for (int o=1;o<64;o<<=1) lmax = fmaxf(lmax, __shfl_xor(lmax, o, 64));
    if (lmax > m_w){
      float al = exp2f(m_w - lmax);
      m_w = lmax;
      #pragma unroll
      for (int r=0;r<4;r++) l_lane[r] *= al;
      #pragma unroll
      for (int t2=0;t2<4;t2++){
        #pragma unroll
        for (int r=0;r<4;r++) oacc[t2][r] *= al;
      }
    }
    #pragma unroll
    for (int t4=0;t4<4;t4++){
      #pragma unroll
      for (int r=0;r<4;r++){
        float e = exp2f(vals[t4*4+r] - m_w);
        l_lane[r] += e;
        Pw[(quad*4+r)*72 + t4*16 + cn] = f2b(e);
      }
    }
    short8 pf0 = *(const short8*)&Pw[cn*72 + kq];
    short8 pf1 = *(const short8*)&Pw[cn*72 + kq + 32];
    #pragma unroll
    for (int t2=0;t2<4;t2++){
      int rr = t2*16 + cn;
      int s0 = ((quad    ) ^ (rr & 7)) * 8;
      int s1 = ((quad + 4) ^ (rr & 7)) * 8;
      short8 v0 = *(const short8*)&Vc[rr*64 + s0];
      short8 v1 = *(const short8*)&Vc[rr*64 + s1];
      oacc[t2] = __builtin_amdgcn_mfma_f32_16x16x32_bf16(pf0, v0, oacc[t2], 0,0,0);
      oacc[t2] = __builtin_amdgcn_mfma_f32_16x16x32_bf16(pf1, v1, oacc[t2], 0,0,0);
    }
  }

  float lrow[4];
  #pragma unroll
  for (int r=0;r<4;r++){
    float l = l_lane[r];
    l += __shfl_xor(l,1,64); l += __shfl_xor(l,2,64);
    l += __shfl_xor(l,4,64); l += __shfl_xor(l,8,64);
    lrow[r] = l;
  }
  size_t ob = (size_t)pidx*4096 + (size_t)(w*16 + quad*4)*64;
  #pragma unroll
  for (int t2=0;t2<4;t2++){
    #pragma unroll
    for (int r=0;r<4;r++)
      obuf[ob + r*64 + t2*16 + cn] = f2b(oacc[t2][r]);
  }
  if (cn == 0){
    #pragma unroll
    for (int r=0;r<4;r++){
      int row64 = w*16 + quad*4 + r;
      mlbuf[((size_t)pidx*64 + row64)*2]   = m_w;
      mlbuf[((size_t)pidx*64 + row64)*2+1] = lrow[r];
    }
  }
}

// ---------------- split-K combine ----------------
template<int CA>
__global__ __launch_bounds__(256) void k_comb(
    const unsigned short* __restrict__ obuf, const float* __restrict__ mlbuf,
    unsigned short* __restrict__ out, int TOTS)
{
  int h = blockIdx.y;
  int row = blockIdx.x*16 + (threadIdx.x >> 4);
  int d0 = (threadIdx.x & 15) * 4;
  int t = row >> 6;
  int klmax0 = 64*t + 64 + CA; if (klmax0 > S) klmax0 = S;
  int nch = (klmax0 + 63) >> 6;
  int nsp = (nch + 7) >> 3;
  int base = 0;
  for (int i = 0; i < t; i++){
    int km = 64*i + 64 + CA; if (km > S) km = S;
    base += (((km + 63) >> 6) + 7) >> 3;
  }
  int row64 = row & 63;
  float mp[4], lp[4];
  float M = -1.0e38f;
  for (int p = 0; p < nsp; p++){
    int pi = h*TOTS + base + p;
    mp[p] = mlbuf[((size_t)pi*64 + row64)*2];
    lp[p] = mlbuf[((size_t)pi*64 + row64)*2+1];
    M = fmaxf(M, mp[p]);
  }
  float L = 0.f;
  float o0=0.f,o1=0.f,o2=0.f,o3=0.f;
  for (int p = 0; p < nsp; p++){
    int pi = h*TOTS + base + p;
    float wgt = exp2f(mp[p] - M);
    L += lp[p]*wgt;
    const unsigned short* op = obuf + (size_t)pi*4096 + row64*64 + d0;
    o0 += b2f(op[0])*wgt; o1 += b2f(op[1])*wgt;
    o2 += b2f(op[2])*wgt; o3 += b2f(op[3])*wgt;
  }
  float inv = 1.0f / L;
  size_t oo = (size_t)row*H + h*HD + d0;
  out[oo]   = f2b(o0*inv); out[oo+1] = f2b(o1*inv);
  out[oo+2] = f2b(o2*inv); out[oo+3] = f2b(o3*inv);
}

extern "C" void kernel_launch(void* const* d_in, const int* in_sizes, int n_in,
                              void* d_out, int out_size, void* d_ws, size_t ws_size,
                              hipStream_t stream)
{
  const void* hs          = d_in[0];
  const void* enc         = d_in[1];
  const void* scorer      = d_in[2];
  const void* ln1_g       = d_in[3];
  const void* ln1_b       = d_in[4];
  const void* c_attn_w    = d_in[5];
  const void* c_attn_b    = d_in[6];
  const void* attn_proj_w = d_in[7];
  const void* attn_proj_b = d_in[8];
  const void* lnx_g       = d_in[9];
  const void* lnx_b       = d_in[10];
  const void* q_attn_w    = d_in[11];
  const void* q_attn_b    = d_in[12];
  const void* x_kv_w      = d_in[13];
  const void* x_kv_b      = d_in[14];
  const void* x_proj_w    = d_in[15];
  const void* x_proj_b    = d_in[16];
  const void* ln2_g       = d_in[17];
  const void* ln2_b       = d_in[18];
  const void* fc_w        = d_in[19];
  const void* fc_b        = d_in[20];
  const void* mlp_proj_w  = d_in[21];
  const void* mlp_proj_b  = d_in[22];
  unsigned short* out = (unsigned short*)d_out;

  char* ws = (char*)d_ws; size_t off = 0;
  auto alloc = [&](size_t bytes)->void*{
    void* p = ws + off; off += (bytes + 255) & ~(size_t)255; return p;
  };
  unsigned short* wT_cattn = (unsigned short*)alloc((size_t)3072*1024*2);
  unsigned short* wT_aproj = (unsigned short*)alloc((size_t)1024*1024*2);
  unsigned short* wT_qattn = (unsigned short*)alloc((size_t)1024*1024*2);
  unsigned short* wT_xkv   = (unsigned short*)alloc((size_t)2048*1024*2);
  unsigned short* wT_xproj = (unsigned short*)alloc((size_t)1024*1024*2);
  unsigned short* wT_fc    = (unsigned short*)alloc((size_t)4096*1024*2);
  unsigned short* wT_mlp   = (unsigned short*)alloc((size_t)1024*4096*2);
  unsigned short* enc_c    = (unsigned short*)alloc((size_t)SEQE*H*2);
  unsigned short* canon    = (unsigned short*)alloc((size_t)32768*2);
  unsigned short* xln      = (unsigned short*)alloc((size_t)S*H*2);
  unsigned short* qkv      = (unsigned short*)alloc((size_t)S*3*H*2);
  unsigned short* attnout  = (unsigned short*)alloc((size_t)S*H*2);
  unsigned short* q2       = (unsigned short*)alloc((size_t)S*H*2);
  unsigned short* kvbuf    = (unsigned short*)alloc((size_t)SEQE*2*H*2);
  unsigned short* vt_self  = (unsigned short*)alloc((size_t)H*S*2);
  unsigned short* vt_cross = (unsigned short*)alloc((size_t)H*SEQE*2);
  unsigned short* fcbuf    = (unsigned short*)alloc((size_t)S*INNER*2);
  float*          hidden   = (float*)alloc((size_t)S*H*4);
  int*            flag     = (int*)alloc(256);

  // flash partials aliased into fcbuf (fcbuf only used in MLP phase)
  unsigned short* obuf  = fcbuf;
  float*          mlbuf = (float*)(fcbuf + (size_t)16*83*4096);

  unsigned short* p = canon;
  auto carve = [&](int n)->unsigned short*{ unsigned short* q = p; p += n; return q; };
  unsigned short* c_ln1g = carve(1024); unsigned short* c_ln1b = carve(1024);
  unsigned short* c_catb = carve(3072); unsigned short* c_aprb = carve(1024);
  unsigned short* c_lnxg = carve(1024); unsigned short* c_lnxb = carve(1024);
  unsigned short* c_qatb = carve(1024); unsigned short* c_xkvb = carve(2048);
  unsigned short* c_xprb = carve(1024); unsigned short* c_ln2g = carve(1024);
  unsigned short* c_ln2b = carve(1024); unsigned short* c_fcb  = carve(4096);
  unsigned short* c_mlpb = carve(1024); unsigned short* c_scor = carve(2048);

  k_sniff<<<1, 256, 0, stream>>>((const unsigned short*)hs, flag);

  // fused weight transposes: tiles = (C/32)*(R/32)
  PrepT pt{};
  const void* tsrc[7] = {c_attn_w, attn_proj_w, q_attn_w, x_kv_w, x_proj_w, fc_w, mlp_proj_w};
  unsigned short* tdst[7] = {wT_cattn, wT_aproj, wT_qattn, wT_xkv, wT_xproj, wT_fc, wT_mlp};
  int tR[7] = {1024,1024,1024,1024,1024,1024,4096};
  int tC[7] = {3072,1024,1024,2048,1024,4096,1024};
  int acc_t = 0;
  for (int i=0;i<7;i++){
    pt.src[i]=tsrc[i]; pt.dst[i]=tdst[i]; pt.R[i]=tR[i]; pt.C[i]=tC[i];
    pt.pre[i]=acc_t; acc_t += (tC[i]>>5)*(tR[i]>>5);
  }
  pt.pre[7]=acc_t;
  k_prep_t<<<acc_t, 256, 0, stream>>>(pt, flag);

  // fused converts (enc, residual init, small params)
  SmallCvt sc{};
  const void* ssrc[14] = {ln1_g, ln1_b, c_attn_b, attn_proj_b, lnx_g, lnx_b,
                          q_attn_b, x_kv_b, x_proj_b, ln2_g, ln2_b, fc_b,
                          mlp_proj_b, scorer};
  unsigned short* sdst[14] = {c_ln1g, c_ln1b, c_catb, c_aprb, c_lnxg, c_lnxb,
                              c_qatb, c_xkvb, c_xprb, c_ln2g, c_ln2b, c_fcb,
                              c_mlpb, c_scor};
  int sn[14] = {1024,1024,3072,1024,1024,1024,1024,2048,1024,1024,1024,4096,1024,2048};
  for (int i=0;i<14;i++){ sc.src[i]=ssrc[i]; sc.dst[i]=sdst[i]; sc.n[i]=sn[i]; }
  k_prep_c<<<16384 + 14, 256, 0, stream>>>(enc, enc_c, hs, hidden, sc, flag);

  // --- self attention ---
  k_layernorm<<<S, 256, 0, stream>>>(hidden, c_ln1g, c_ln1b, xln);
  k_gemm64<<<dim3(3072/128, S/64), 256, 0, stream>>>(xln, wT_cattn, c_catb,
      qkv, nullptr, S, 3072, 1024, 4, flag, 2048, vt_self);
  k_flash2<0,0><<<dim3(32, NHEAD, 4), 256, 0, stream>>>(
      qkv, 3*H, qkv + 1024, 3*H, vt_self, nullptr, obuf, mlbuf, 80);
  k_comb<0><<<dim3(S/16, NHEAD), 256, 0, stream>>>(obuf, mlbuf, attnout, 80);
  k_gemm64<<<dim3(1024/128, S/64), 256, 0, stream>>>(attnout, wT_aproj, c_aprb,
      nullptr, hidden, S, 1024, 1024, 2, flag, 0, nullptr);

  // --- cross attention ---
  k_layernorm<<<S, 256, 0, stream>>>(hidden, c_lnxg, c_lnxb, xln);
  k_gemm64<<<dim3(1024/128, S/64), 256, 0, stream>>>(xln, wT_qattn, c_qatb,
      q2, nullptr, S, 1024, 1024, 0, flag, 0, nullptr);
  k_gemm64<<<dim3(2048/128, SEQE/64), 256, 0, stream>>>(enc_c, wT_xkv, c_xkvb,
      kvbuf, nullptr, SEQE, 2048, 1024, 4, flag, 1024, vt_cross);
  k_flash2<2,1><<<dim3(32, NHEAD, 4), 256, 0, stream>>>(
      q2, H, kvbuf, 2*H, vt_cross, c_scor, obuf, mlbuf, 83);
  k_comb<2><<<dim3(S/16, NHEAD), 256, 0, stream>>>(obuf, mlbuf, attnout, 83);
  k_gemm64<<<dim3(1024/128, S/64), 256, 0, stream>>>(attnout, wT_xproj, c_xprb,
      nullptr, hidden, S, 1024, 1024, 2, flag, 0, nullptr);

  // --- MLP ---
  k_layernorm<<<S, 256, 0, stream>>>(hidden, c_ln2g, c_ln2b, xln);
  k_gemm64<<<dim3(INNER/128, S/64), 256, 0, stream>>>(xln, wT_fc, c_fcb,
      fcbuf, nullptr, S, INNER, 1024, 1, flag, 0, nullptr);
  k_gemm64<<<dim3(1024/128, S/64), 256, 0, stream>>>(fcbuf, wT_mlp, c_mlpb,
      out, hidden, S, 1024, INNER, 3, flag, 0, nullptr);
}

// Round 8
// 467.061 us; speedup vs baseline: 2.7897x; 1.0942x over previous
//
#include <hip/hip_runtime.h>
#include <stdint.h>

#define H     1024
#define S     2048
#define SEQE  2048
#define NHEAD 16
#define HD    64
#define INNER 4096
#define EPSLN 1e-5f
#define LOG2E 1.44269504089f
#define SCALE2 (0.125f * LOG2E)

typedef __attribute__((ext_vector_type(8))) short short8;
typedef __attribute__((ext_vector_type(4))) float floatx4;

__device__ __forceinline__ float b2f(unsigned short u){
  union { unsigned int i; float f; } v; v.i = ((unsigned int)u) << 16; return v.f;
}
__device__ __forceinline__ unsigned short f2b(float f){
  union { float f; unsigned int i; } v; v.f = f;
  unsigned int x = v.i;
  unsigned int r = (x + 0x7FFFu + ((x >> 16) & 1u)) >> 16;
  return (unsigned short)r;
}
__device__ __forceinline__ float fexp2(float x){ return __builtin_amdgcn_exp2f(x); }
__device__ __forceinline__ float gelu_tanh(float x){
  float x3 = x*x*x;
  float t = tanhf(0.7978845608028654f*(x + 0.044715f*x3));
  return 0.5f*x*(1.0f+t);
}

// async global->LDS, 16B per lane; LDS dest = wave-uniform base + lane*16
__device__ __forceinline__ void gld16(const unsigned short* g, unsigned short* l){
  __builtin_amdgcn_global_load_lds(
      (const __attribute__((address_space(1))) unsigned int*)g,
      (__attribute__((address_space(3))) unsigned int*)l,
      16, 0, 0);
}

// ---------------- dtype sniff ----------------
__global__ __launch_bounds__(256) void k_sniff(
    const unsigned short* __restrict__ p, int* __restrict__ flag){
  __shared__ int any;
  if (threadIdx.x == 0) any = 0;
  __syncthreads();
  int bad = 0;
  for (int i = threadIdx.x; i < 8192; i += 256){
    float v = b2f(p[i]);
    if (!(fabsf(v) < 1e6f)) bad = 1;
  }
  if (bad) any = 1;
  __syncthreads();
  if (threadIdx.x == 0) flag[0] = any;
}

// ---------------- fused weight transposes ----------------
struct PrepT {
  const void* src[7];
  unsigned short* dst[7];
  int R[7], C[7];
  int pre[8];
};
__global__ __launch_bounds__(256) void k_prep_t(PrepT d, const int* __restrict__ flag){
  __shared__ unsigned short t[32][33];
  int b = blockIdx.x;
  int m = 0;
  while (b >= d.pre[m+1]) m++;
  int ti = b - d.pre[m];
  int R = d.R[m], C = d.C[m];
  int tx = threadIdx.x & 31, ty = threadIdx.x >> 5;
  int tilesx = C >> 5;
  int bc = (ti % tilesx) << 5, br = (ti / tilesx) << 5;
  const float* sf = (const float*)d.src[m];
  const unsigned short* sb = (const unsigned short*)d.src[m];
  unsigned short* dst = d.dst[m];
  int fl = flag[0];
  #pragma unroll
  for (int i = 0; i < 4; i++){
    size_t idx = (size_t)(br + ty + i*8) * C + bc + tx;
    t[ty + i*8][tx] = fl ? f2b(sf[idx]) : sb[idx];
  }
  __syncthreads();
  #pragma unroll
  for (int i = 0; i < 4; i++)
    dst[(size_t)(bc + ty + i*8) * R + br + tx] = t[tx][ty + i*8];
}

// ---------------- fused converts ----------------
struct SmallCvt {
  const void* src[16];
  unsigned short* dst[16];
  int n[16];
};
__global__ __launch_bounds__(256) void k_prep_c(
    const void* __restrict__ enc, unsigned short* __restrict__ enc_c,
    const void* __restrict__ hsv, float* __restrict__ hidden,
    SmallCvt sc, const int* __restrict__ flag){
  int b = blockIdx.x, tid = threadIdx.x;
  int fl = flag[0];
  if (b < 8192){
    int i = b*256 + tid;
    enc_c[i] = fl ? f2b(((const float*)enc)[i]) : ((const unsigned short*)enc)[i];
  } else if (b < 16384){
    int i = (b - 8192)*256 + tid;
    hidden[i] = fl ? ((const float*)hsv)[i] : b2f(((const unsigned short*)hsv)[i]);
  } else {
    int t = b - 16384;
    const float* sf = (const float*)sc.src[t];
    const unsigned short* sb = (const unsigned short*)sc.src[t];
    unsigned short* d = sc.dst[t];
    for (int i = tid; i < sc.n[t]; i += 256)
      d[i] = fl ? f2b(sf[i]) : sb[i];
  }
}

// ---------------- LayerNorm ----------------
__global__ __launch_bounds__(256) void k_layernorm(
    const float* __restrict__ x,
    const unsigned short* __restrict__ g, const unsigned short* __restrict__ bb,
    unsigned short* __restrict__ y){
  __shared__ float scratch[4];
  int row = blockIdx.x, tid = threadIdx.x;
  float v[4];
  #pragma unroll
  for (int i=0;i<4;i++) v[i] = x[(size_t)row*H + tid + i*256];
  float s = v[0]+v[1]+v[2]+v[3];
  for (int o=32;o;o>>=1) s += __shfl_xor(s,o,64);
  int wid = tid>>6, lane = tid&63;
  if (lane==0) scratch[wid]=s;
  __syncthreads();
  float mu = (scratch[0]+scratch[1]+scratch[2]+scratch[3]) * (1.0f/H);
  __syncthreads();
  float q = 0.f;
  #pragma unroll
  for (int i=0;i<4;i++){ float d=v[i]-mu; q += d*d; }
  for (int o=32;o;o>>=1) q += __shfl_xor(q,o,64);
  if (lane==0) scratch[wid]=q;
  __syncthreads();
  float var = (scratch[0]+scratch[1]+scratch[2]+scratch[3]) * (1.0f/H);
  float rstd = rsqrtf(var + EPSLN);
  #pragma unroll
  for (int i=0;i<4;i++){
    int idx = tid + i*256;
    float o = (v[i]-mu)*rstd*b2f(g[idx]) + b2f(bb[idx]);
    y[(size_t)row*H + idx] = f2b(o);
  }
}

// ---------------- bf16 MFMA GEMM, 64x128 tile, BK=64, dbuf async staging ----------------
__global__ __launch_bounds__(256) void k_gemm64(
    const unsigned short* __restrict__ A, const unsigned short* __restrict__ BT,
    const unsigned short* __restrict__ bias,
    unsigned short* __restrict__ outb, float* __restrict__ resid,
    int M, int N, int K, int mode, const int* __restrict__ flag,
    int vcol0, unsigned short* __restrict__ vtout)
{
  __shared__ __align__(16) unsigned short As[2][64*64];
  __shared__ __align__(16) unsigned short Bs[2][128*64];
  int tid = threadIdx.x;
  int bm0 = blockIdx.y * 64, bn0 = blockIdx.x * 128;
  int wid = tid >> 6, lane = tid & 63;
  int wm = (wid & 1) * 32, wn = (wid >> 1) * 64;
  int fl = (mode == 3) ? flag[0] : 0;
  floatx4 acc[2][4] = {};

  const unsigned short* gp[6];
  int lofs[6];
  int aseg[6];
  int lrow = lane >> 3, lchunk = (lane & 7) ^ lrow;
  #pragma unroll
  for (int t = 0; t < 6; t++){
    int seg = wid * 6 + t;
    if (seg < 8){
      gp[t] = A + (size_t)(bm0 + seg*8 + lrow) * K + lchunk*8;
      lofs[t] = seg * 512;
      aseg[t] = 1;
    } else {
      int s = seg - 8;
      gp[t] = BT + (size_t)(bn0 + s*8 + lrow) * K + lchunk*8;
      lofs[t] = s * 512;
      aseg[t] = 0;
    }
  }

  #pragma unroll
  for (int t = 0; t < 6; t++)
    gld16(gp[t], (aseg[t] ? As[0] : Bs[0]) + lofs[t]);

  int mrow = lane & 15, quad = lane >> 4;
  int ib = 0;
  for (int kt = 0; kt < K; kt += 64, ib ^= 1){
    __syncthreads();
    if (kt + 64 < K){
      #pragma unroll
      for (int t = 0; t < 6; t++)
        gld16(gp[t] + kt + 64, (aseg[t] ? As[ib^1] : Bs[ib^1]) + lofs[t]);
    }
    const unsigned short* Ac = As[ib];
    const unsigned short* Bc = Bs[ib];
    #pragma unroll
    for (int k2 = 0; k2 < 2; k2++){
      short8 af[2], bf[4];
      #pragma unroll
      for (int i = 0; i < 2; i++){
        int r = wm + i*16 + mrow;
        int slot = (k2*4 + quad) ^ (r & 7);
        af[i] = *(const short8*)&Ac[r*64 + slot*8];
      }
      #pragma unroll
      for (int j = 0; j < 4; j++){
        int r = wn + j*16 + mrow;
        int slot = (k2*4 + quad) ^ (r & 7);
        bf[j] = *(const short8*)&Bc[r*64 + slot*8];
      }
      #pragma unroll
      for (int i = 0; i < 2; i++){
        #pragma unroll
        for (int j = 0; j < 4; j++){
          acc[i][j] = __builtin_amdgcn_mfma_f32_16x16x32_bf16(af[i], bf[j], acc[i][j], 0,0,0);
        }
      }
    }
  }

  int colb = mrow, rowb = quad * 4;
  #pragma unroll
  for (int i=0;i<2;i++){
    #pragma unroll
    for (int j=0;j<4;j++){
      int col = bn0 + wn + j*16 + colb;
      float bv = b2f(bias[col]);
      int row0 = bm0 + wm + i*16 + rowb;
      if (mode == 4 && col >= vcol0){
        ushort4 uv;
        uv.x = f2b(acc[i][j][0] + bv);
        uv.y = f2b(acc[i][j][1] + bv);
        uv.z = f2b(acc[i][j][2] + bv);
        uv.w = f2b(acc[i][j][3] + bv);
        *(ushort4*)(vtout + (size_t)(col - vcol0)*M + row0) = uv;
      } else {
        #pragma unroll
        for (int rr=0;rr<4;rr++){
          int row = row0 + rr;
          float v = acc[i][j][rr] + bv;
          size_t off = (size_t)row*N + col;
          if      (mode == 0 || mode == 4){ outb[off] = f2b(v); }
          else if (mode == 1){ outb[off] = f2b(gelu_tanh(v)); }
          else if (mode == 2){ resid[off] += v; }
          else {
            float o = v + resid[off];
            if (fl) ((float*)outb)[off] = o;
            else    outb[off] = f2b(o);
          }
        }
      }
    }
  }
}

// ---------------- bf16 MFMA GEMM, 64x64 tile (for N=1024 GEMMs: 512 blocks, 2/CU) ----
// modes: 0 = bf16 out, 2 = resid += v, 3 = out = v + resid (flag dtype)
__global__ __launch_bounds__(256) void k_gemm64s(
    const unsigned short* __restrict__ A, const unsigned short* __restrict__ BT,
    const unsigned short* __restrict__ bias,
    unsigned short* __restrict__ outb, float* __restrict__ resid,
    int M, int N, int K, int mode, const int* __restrict__ flag)
{
  __shared__ __align__(16) unsigned short As[2][64*64];
  __shared__ __align__(16) unsigned short Bs[2][64*64];
  int tid = threadIdx.x;
  int bm0 = blockIdx.y * 64, bn0 = blockIdx.x * 64;
  int wid = tid >> 6, lane = tid & 63;
  int wm = wid * 16;
  int fl = (mode == 3) ? flag[0] : 0;
  floatx4 acc[4] = {};

  // 16 segments of 8 rows x 64 cols; wave w -> segs [4w, 4w+4)
  const unsigned short* gp[4];
  int lofs[4];
  int aseg[4];
  int lrow = lane >> 3, lchunk = (lane & 7) ^ lrow;
  #pragma unroll
  for (int t = 0; t < 4; t++){
    int seg = wid * 4 + t;
    if (seg < 8){
      gp[t] = A + (size_t)(bm0 + seg*8 + lrow) * K + lchunk*8;
      lofs[t] = seg * 512;
      aseg[t] = 1;
    } else {
      int s = seg - 8;
      gp[t] = BT + (size_t)(bn0 + s*8 + lrow) * K + lchunk*8;
      lofs[t] = s * 512;
      aseg[t] = 0;
    }
  }

  #pragma unroll
  for (int t = 0; t < 4; t++)
    gld16(gp[t], (aseg[t] ? As[0] : Bs[0]) + lofs[t]);

  int mrow = lane & 15, quad = lane >> 4;
  int ib = 0;
  for (int kt = 0; kt < K; kt += 64, ib ^= 1){
    __syncthreads();
    if (kt + 64 < K){
      #pragma unroll
      for (int t = 0; t < 4; t++)
        gld16(gp[t] + kt + 64, (aseg[t] ? As[ib^1] : Bs[ib^1]) + lofs[t]);
    }
    const unsigned short* Ac = As[ib];
    const unsigned short* Bc = Bs[ib];
    #pragma unroll
    for (int k2 = 0; k2 < 2; k2++){
      short8 af, bf[4];
      {
        int r = wm + mrow;
        int slot = (k2*4 + quad) ^ (r & 7);
        af = *(const short8*)&Ac[r*64 + slot*8];
      }
      #pragma unroll
      for (int j = 0; j < 4; j++){
        int r = j*16 + mrow;
        int slot = (k2*4 + quad) ^ (r & 7);
        bf[j] = *(const short8*)&Bc[r*64 + slot*8];
      }
      #pragma unroll
      for (int j = 0; j < 4; j++)
        acc[j] = __builtin_amdgcn_mfma_f32_16x16x32_bf16(af, bf[j], acc[j], 0,0,0);
    }
  }

  int colb = mrow, rowb = quad * 4;
  #pragma unroll
  for (int j=0;j<4;j++){
    int col = bn0 + j*16 + colb;
    float bv = b2f(bias[col]);
    int row0 = bm0 + wm + rowb;
    #pragma unroll
    for (int rr=0;rr<4;rr++){
      int row = row0 + rr;
      float v = acc[j][rr] + bv;
      size_t off = (size_t)row*N + col;
      if      (mode == 0){ outb[off] = f2b(v); }
      else if (mode == 2){ resid[off] += v; }
      else {
        float o = v + resid[off];
        if (fl) ((float*)outb)[off] = o;
        else    outb[off] = f2b(o);
      }
    }
  }
}

// ---------------- split-K flash attention (dbuf staging, fast exp2, quad max) --------
template<int CA, int SCOR>
__global__ __launch_bounds__(256) void k_flash2(
    const unsigned short* __restrict__ qb, int qstride,
    const unsigned short* __restrict__ kb, int kstride,
    const unsigned short* __restrict__ vt,
    const unsigned short* __restrict__ scorer,
    unsigned short* __restrict__ obuf, float* __restrict__ mlbuf, int TOTS)
{
  int t = blockIdx.x, h = blockIdx.y, sp = blockIdx.z;
  int klmax0 = 64*t + 64 + CA; if (klmax0 > S) klmax0 = S;
  int nch = (klmax0 + 63) >> 6;
  int nsp = (nch + 7) >> 3;
  if (sp >= nsp) return;
  int base = 0;
  for (int i = 0; i < t; i++){
    int km = 64*i + 64 + CA; if (km > S) km = S;
    base += (((km + 63) >> 6) + 7) >> 3;
  }
  int pidx = h*TOTS + base + sp;
  int c0 = sp*8, c1 = c0 + 8; if (c1 > nch) c1 = nch;

  __shared__ __align__(16) unsigned short Ks[2][64*64];
  __shared__ __align__(16) unsigned short VTs[2][64*64];
  __shared__ __align__(16) unsigned short Ps[4][16*72];
  __shared__ float scs[2][64];
  int tid = threadIdx.x;
  int q0 = t*64;
  int w = tid >> 6, lane = tid & 63;
  int cn = lane & 15, quad = lane >> 4, kq = quad * 8;
  unsigned short* Pw = Ps[w];
  int srow0 = w*16;
  int lr = lane >> 3;
  int lc = ((lane & 7) ^ lr) * 8;
  const unsigned short* kg0 = kb + (size_t)(srow0 + lr) * kstride + h*HD + lc;
  const unsigned short* kg1 = kb + (size_t)(srow0 + 8 + lr) * kstride + h*HD + lc;
  const unsigned short* vg0 = vt + (size_t)(h*HD + srow0 + lr) * S + lc;
  const unsigned short* vg1 = vt + (size_t)(h*HD + srow0 + 8 + lr) * S + lc;

  const unsigned short* qrow = qb + (size_t)(q0 + w*16 + cn) * qstride + h*HD;
  short8 qf0 = *(const short8*)(qrow + kq);
  short8 qf1 = *(const short8*)(qrow + kq + 32);
  floatx4 oacc[4] = {};
  float l_lane[4] = {0,0,0,0};
  float m_w = -1.0e38f;
  int qmr = q0 + w*16 + quad*4;

  {
    int kc = c0 * 64;
    gld16(kg0 + (size_t)kc * kstride, Ks[0] + srow0*64);
    gld16(kg1 + (size_t)kc * kstride, Ks[0] + (srow0 + 8)*64);
    gld16(vg0 + kc, VTs[0] + srow0*64);
    gld16(vg1 + kc, VTs[0] + (srow0 + 8)*64);
    if (SCOR && tid < 64) scs[0][tid] = b2f(scorer[kc + tid]) * LOG2E;
  }

  int ib = 0;
  for (int ci = c0; ci < c1; ci++, ib ^= 1){
    __syncthreads();
    if (ci + 1 < c1){
      int kn2 = (ci + 1) * 64;
      gld16(kg0 + (size_t)kn2 * kstride, Ks[ib^1] + srow0*64);
      gld16(kg1 + (size_t)kn2 * kstride, Ks[ib^1] + (srow0 + 8)*64);
      gld16(vg0 + kn2, VTs[ib^1] + srow0*64);
      gld16(vg1 + kn2, VTs[ib^1] + (srow0 + 8)*64);
      if (SCOR && tid < 64) scs[ib^1][tid] = b2f(scorer[kn2 + tid]) * LOG2E;
    }
    int kc = ci * 64;
    const unsigned short* Kc = Ks[ib];
    const unsigned short* Vc = VTs[ib];
    const float* scc = scs[ib];

    floatx4 sv[4] = {};
    #pragma unroll
    for (int t4=0;t4<4;t4++){
      int rr = t4*16 + cn;
      int s0 = ((quad    ) ^ (rr & 7)) * 8;
      int s1 = ((quad + 4) ^ (rr & 7)) * 8;
      short8 b0 = *(const short8*)&Kc[rr*64 + s0];
      short8 b1 = *(const short8*)&Kc[rr*64 + s1];
      sv[t4] = __builtin_amdgcn_mfma_f32_16x16x32_bf16(qf0, b0, sv[t4], 0,0,0);
      sv[t4] = __builtin_amdgcn_mfma_f32_16x16x32_bf16(qf1, b1, sv[t4], 0,0,0);
    }

    float vals[16];
    float lmax = -1.0e38f;
    if (kc + 63 > q0 + w*16 + CA){          // wave-uniform: diagonal (masked) chunk
      #pragma unroll
      for (int t4=0;t4<4;t4++){
        #pragma unroll
        for (int r=0;r<4;r++){
          float s = sv[t4][r] * SCALE2;
          if (SCOR) s += scc[t4*16 + cn];
          int kn = kc + t4*16 + cn;
          s = (kn <= qmr + r + CA) ? s : -1.0e38f;
          vals[t4*4+r] = s;
          lmax = fmaxf(lmax, s);
        }
      }
    } else {
      #pragma unroll
      for (int t4=0;t4<4;t4++){
        #pragma unroll
        for (int r=0;r<4;r++){
          float s = sv[t4][r] * SCALE2;
          if (SCOR) s += scc[t4*16 + cn];
          vals[t4*4+r] = s;
          lmax = fmaxf(lmax, s);
        }
      }
    }
    // per-quad-group max (16 lanes share all cols of rows quad*4..+3): DPP-fast shuffles
    lmax = fmaxf(lmax, __shfl_xor(lmax,1,64));
    lmax = fmaxf(lmax, __shfl_xor(lmax,2,64));
    lmax = fmaxf(lmax, __shfl_xor(lmax,4,64));
    lmax = fmaxf(lmax, __shfl_xor(lmax,8,64));
    if (lmax > m_w){
      float al = fexp2(m_w - lmax);
      m_w = lmax;
      #pragma unroll
      for (int r=0;r<4;r++) l_lane[r] *= al;
      #pragma unroll
      for (int t2=0;t2<4;t2++){
        #pragma unroll
        for (int r=0;r<4;r++) oacc[t2][r] *= al;
      }
    }
    #pragma unroll
    for (int t4=0;t4<4;t4++){
      #pragma unroll
      for (int r=0;r<4;r++){
        float e = fexp2(vals[t4*4+r] - m_w);
        l_lane[r] += e;
        Pw[(quad*4+r)*72 + t4*16 + cn] = f2b(e);
      }
    }
    short8 pf0 = *(const short8*)&Pw[cn*72 + kq];
    short8 pf1 = *(const short8*)&Pw[cn*72 + kq + 32];
    #pragma unroll
    for (int t2=0;t2<4;t2++){
      int rr = t2*16 + cn;
      int s0 = ((quad    ) ^ (rr & 7)) * 8;
      int s1 = ((quad + 4) ^ (rr & 7)) * 8;
      short8 v0 = *(const short8*)&Vc[rr*64 + s0];
      short8 v1 = *(const short8*)&Vc[rr*64 + s1];
      oacc[t2] = __builtin_amdgcn_mfma_f32_16x16x32_bf16(pf0, v0, oacc[t2], 0,0,0);
      oacc[t2] = __builtin_amdgcn_mfma_f32_16x16x32_bf16(pf1, v1, oacc[t2], 0,0,0);
    }
  }

  float lrow[4];
  #pragma unroll
  for (int r=0;r<4;r++){
    float l = l_lane[r];
    l += __shfl_xor(l,1,64); l += __shfl_xor(l,2,64);
    l += __shfl_xor(l,4,64); l += __shfl_xor(l,8,64);
    lrow[r] = l;
  }
  size_t ob = (size_t)pidx*4096 + (size_t)(w*16 + quad*4)*64;
  #pragma unroll
  for (int t2=0;t2<4;t2++){
    #pragma unroll
    for (int r=0;r<4;r++)
      obuf[ob + r*64 + t2*16 + cn] = f2b(oacc[t2][r]);
  }
  if (cn == 0){
    #pragma unroll
    for (int r=0;r<4;r++){
      int row64 = w*16 + quad*4 + r;
      mlbuf[((size_t)pidx*64 + row64)*2]   = m_w;
      mlbuf[((size_t)pidx*64 + row64)*2+1] = lrow[r];
    }
  }
}

// ---------------- split-K combine ----------------
template<int CA>
__global__ __launch_bounds__(256) void k_comb(
    const unsigned short* __restrict__ obuf, const float* __restrict__ mlbuf,
    unsigned short* __restrict__ out, int TOTS)
{
  int h = blockIdx.y;
  int row = blockIdx.x*16 + (threadIdx.x >> 4);
  int d0 = (threadIdx.x & 15) * 4;
  int t = row >> 6;
  int klmax0 = 64*t + 64 + CA; if (klmax0 > S) klmax0 = S;
  int nch = (klmax0 + 63) >> 6;
  int nsp = (nch + 7) >> 3;
  int base = 0;
  for (int i = 0; i < t; i++){
    int km = 64*i + 64 + CA; if (km > S) km = S;
    base += (((km + 63) >> 6) + 7) >> 3;
  }
  int row64 = row & 63;
  float mp[4], lp[4];
  float M = -1.0e38f;
  for (int p = 0; p < nsp; p++){
    int pi = h*TOTS + base + p;
    mp[p] = mlbuf[((size_t)pi*64 + row64)*2];
    lp[p] = mlbuf[((size_t)pi*64 + row64)*2+1];
    M = fmaxf(M, mp[p]);
  }
  float L = 0.f;
  float o0=0.f,o1=0.f,o2=0.f,o3=0.f;
  for (int p = 0; p < nsp; p++){
    int pi = h*TOTS + base + p;
    float wgt = fexp2(mp[p] - M);
    L += lp[p]*wgt;
    const unsigned short* op = obuf + (size_t)pi*4096 + row64*64 + d0;
    o0 += b2f(op[0])*wgt; o1 += b2f(op[1])*wgt;
    o2 += b2f(op[2])*wgt; o3 += b2f(op[3])*wgt;
  }
  float inv = 1.0f / L;
  size_t oo = (size_t)row*H + h*HD + d0;
  out[oo]   = f2b(o0*inv); out[oo+1] = f2b(o1*inv);
  out[oo+2] = f2b(o2*inv); out[oo+3] = f2b(o3*inv);
}

extern "C" void kernel_launch(void* const* d_in, const int* in_sizes, int n_in,
                              void* d_out, int out_size, void* d_ws, size_t ws_size,
                              hipStream_t stream)
{
  const void* hs          = d_in[0];
  const void* enc         = d_in[1];
  const void* scorer      = d_in[2];
  const void* ln1_g       = d_in[3];
  const void* ln1_b       = d_in[4];
  const void* c_attn_w    = d_in[5];
  const void* c_attn_b    = d_in[6];
  const void* attn_proj_w = d_in[7];
  const void* attn_proj_b = d_in[8];
  const void* lnx_g       = d_in[9];
  const void* lnx_b       = d_in[10];
  const void* q_attn_w    = d_in[11];
  const void* q_attn_b    = d_in[12];
  const void* x_kv_w      = d_in[13];
  const void* x_kv_b      = d_in[14];
  const void* x_proj_w    = d_in[15];
  const void* x_proj_b    = d_in[16];
  const void* ln2_g       = d_in[17];
  const void* ln2_b       = d_in[18];
  const void* fc_w        = d_in[19];
  const void* fc_b        = d_in[20];
  const void* mlp_proj_w  = d_in[21];
  const void* mlp_proj_b  = d_in[22];
  unsigned short* out = (unsigned short*)d_out;

  char* ws = (char*)d_ws; size_t off = 0;
  auto alloc = [&](size_t bytes)->void*{
    void* p = ws + off; off += (bytes + 255) & ~(size_t)255; return p;
  };
  unsigned short* wT_cattn = (unsigned short*)alloc((size_t)3072*1024*2);
  unsigned short* wT_aproj = (unsigned short*)alloc((size_t)1024*1024*2);
  unsigned short* wT_qattn = (unsigned short*)alloc((size_t)1024*1024*2);
  unsigned short* wT_xkv   = (unsigned short*)alloc((size_t)2048*1024*2);
  unsigned short* wT_xproj = (unsigned short*)alloc((size_t)1024*1024*2);
  unsigned short* wT_fc    = (unsigned short*)alloc((size_t)4096*1024*2);
  unsigned short* wT_mlp   = (unsigned short*)alloc((size_t)1024*4096*2);
  unsigned short* enc_c    = (unsigned short*)alloc((size_t)SEQE*H*2);
  unsigned short* canon    = (unsigned short*)alloc((size_t)32768*2);
  unsigned short* xln      = (unsigned short*)alloc((size_t)S*H*2);
  unsigned short* qkv      = (unsigned short*)alloc((size_t)S*3*H*2);
  unsigned short* attnout  = (unsigned short*)alloc((size_t)S*H*2);
  unsigned short* q2       = (unsigned short*)alloc((size_t)S*H*2);
  unsigned short* kvbuf    = (unsigned short*)alloc((size_t)SEQE*2*H*2);
  unsigned short* vt_self  = (unsigned short*)alloc((size_t)H*S*2);
  unsigned short* vt_cross = (unsigned short*)alloc((size_t)H*SEQE*2);
  unsigned short* fcbuf    = (unsigned short*)alloc((size_t)S*INNER*2);
  float*          hidden   = (float*)alloc((size_t)S*H*4);
  int*            flag     = (int*)alloc(256);

  unsigned short* obuf  = fcbuf;
  float*          mlbuf = (float*)(fcbuf + (size_t)16*83*4096);

  unsigned short* p = canon;
  auto carve = [&](int n)->unsigned short*{ unsigned short* q = p; p += n; return q; };
  unsigned short* c_ln1g = carve(1024); unsigned short* c_ln1b = carve(1024);
  unsigned short* c_catb = carve(3072); unsigned short* c_aprb = carve(1024);
  unsigned short* c_lnxg = carve(1024); unsigned short* c_lnxb = carve(1024);
  unsigned short* c_qatb = carve(1024); unsigned short* c_xkvb = carve(2048);
  unsigned short* c_xprb = carve(1024); unsigned short* c_ln2g = carve(1024);
  unsigned short* c_ln2b = carve(1024); unsigned short* c_fcb  = carve(4096);
  unsigned short* c_mlpb = carve(1024); unsigned short* c_scor = carve(2048);

  k_sniff<<<1, 256, 0, stream>>>((const unsigned short*)hs, flag);

  PrepT pt{};
  const void* tsrc[7] = {c_attn_w, attn_proj_w, q_attn_w, x_kv_w, x_proj_w, fc_w, mlp_proj_w};
  unsigned short* tdst[7] = {wT_cattn, wT_aproj, wT_qattn, wT_xkv, wT_xproj, wT_fc, wT_mlp};
  int tR[7] = {1024,1024,1024,1024,1024,1024,4096};
  int tC[7] = {3072,1024,1024,2048,1024,4096,1024};
  int acc_t = 0;
  for (int i=0;i<7;i++){
    pt.src[i]=tsrc[i]; pt.dst[i]=tdst[i]; pt.R[i]=tR[i]; pt.C[i]=tC[i];
    pt.pre[i]=acc_t; acc_t += (tC[i]>>5)*(tR[i]>>5);
  }
  pt.pre[7]=acc_t;
  k_prep_t<<<acc_t, 256, 0, stream>>>(pt, flag);

  SmallCvt sc{};
  const void* ssrc[14] = {ln1_g, ln1_b, c_attn_b, attn_proj_b, lnx_g, lnx_b,
                          q_attn_b, x_kv_b, x_proj_b, ln2_g, ln2_b, fc_b,
                          mlp_proj_b, scorer};
  unsigned short* sdst[14] = {c_ln1g, c_ln1b, c_catb, c_aprb, c_lnxg, c_lnxb,
                              c_qatb, c_xkvb, c_xprb, c_ln2g, c_ln2b, c_fcb,
                              c_mlpb, c_scor};
  int sn[14] = {1024,1024,3072,1024,1024,1024,1024,2048,1024,1024,1024,4096,1024,2048};
  for (int i=0;i<14;i++){ sc.src[i]=ssrc[i]; sc.dst[i]=sdst[i]; sc.n[i]=sn[i]; }
  k_prep_c<<<16384 + 14, 256, 0, stream>>>(enc, enc_c, hs, hidden, sc, flag);

  // --- self attention ---
  k_layernorm<<<S, 256, 0, stream>>>(hidden, c_ln1g, c_ln1b, xln);
  k_gemm64<<<dim3(3072/128, S/64), 256, 0, stream>>>(xln, wT_cattn, c_catb,
      qkv, nullptr, S, 3072, 1024, 4, flag, 2048, vt_self);
  k_flash2<0,0><<<dim3(32, NHEAD, 4), 256, 0, stream>>>(
      qkv, 3*H, qkv + 1024, 3*H, vt_self, nullptr, obuf, mlbuf, 80);
  k_comb<0><<<dim3(S/16, NHEAD), 256, 0, stream>>>(obuf, mlbuf, attnout, 80);
  k_gemm64s<<<dim3(1024/64, S/64), 256, 0, stream>>>(attnout, wT_aproj, c_aprb,
      nullptr, hidden, S, 1024, 1024, 2, flag);

  // --- cross attention ---
  k_layernorm<<<S, 256, 0, stream>>>(hidden, c_lnxg, c_lnxb, xln);
  k_gemm64s<<<dim3(1024/64, S/64), 256, 0, stream>>>(xln, wT_qattn, c_qatb,
      q2, nullptr, S, 1024, 1024, 0, flag);
  k_gemm64<<<dim3(2048/128, SEQE/64), 256, 0, stream>>>(enc_c, wT_xkv, c_xkvb,
      kvbuf, nullptr, SEQE, 2048, 1024, 4, flag, 1024, vt_cross);
  k_flash2<2,1><<<dim3(32, NHEAD, 4), 256, 0, stream>>>(
      q2, H, kvbuf, 2*H, vt_cross, c_scor, obuf, mlbuf, 83);
  k_comb<2><<<dim3(S/16, NHEAD), 256, 0, stream>>>(obuf, mlbuf, attnout, 83);
  k_gemm64s<<<dim3(1024/64, S/64), 256, 0, stream>>>(attnout, wT_xproj, c_xprb,
      nullptr, hidden, S, 1024, 1024, 2, flag);

  // --- MLP ---
  k_layernorm<<<S, 256, 0, stream>>>(hidden, c_ln2g, c_ln2b, xln);
  k_gemm64<<<dim3(INNER/128, S/64), 256, 0, stream>>>(xln, wT_fc, c_fcb,
      fcbuf, nullptr, S, INNER, 1024, 1, flag, 0, nullptr);
  k_gemm64s<<<dim3(1024/64, S/64), 256, 0, stream>>>(fcbuf, wT_mlp, c_mlpb,
      out, hidden, S, 1024, INNER, 3, flag);
}